// Round 1
// baseline (259.767 us; speedup 1.0000x reference)
//
#include <hip/hip_runtime.h>

// PairWeightedAveraging: m[1,S,N,Dm], z[1,N,N,Dz] -> out[1,S,N,Dm]
// S=256 N=512 Dm=64 Dz=128 H=8 HD=32
// Pipeline (all bf16 MFMA, fragment-native layouts, no LDS in GEMMs):
//  k0: pre-swizzle [Wm|Wg] and Wo into per-lane fragment tables
//  k1: LN(z) + b=zn*Wz + softmax_j -> w[h][i][j] bf16
//  k2a: LN(m) -> mn bf16
//  k2b: v,g = mn @ [Wm|Wg]; v -> Vf frag layout, g=sigmoid -> g2[h][i][s*32+k]
//  k3: per-head GEMM o = w @ v, gate with g2 IN-PLACE (og overwrites g2)
//  k4: out = og @ Wo (og layout is already A-fragment-native)

#define S_DIM 256
#define N_DIM 512
#define DM 64
#define DZ 128
#define NH 8
#define HD 32
#define HK 256
#define NP 8192  // S_DIM*HD

typedef unsigned int   u32;
typedef unsigned short u16;
typedef __bf16 bf16x8 __attribute__((ext_vector_type(8)));
typedef float  f32x4  __attribute__((ext_vector_type(4)));
typedef u32    u32x4  __attribute__((ext_vector_type(4)));

__device__ __forceinline__ u16 f2bf(float f) {
  u32 u = __builtin_bit_cast(u32, f);
  return (u16)((u + 0x7FFFu + ((u >> 16) & 1u)) >> 16);  // RNE
}
__device__ __forceinline__ float bf2f(u16 h) {
  u32 u = ((u32)h) << 16;
  return __builtin_bit_cast(float, u);
}
__device__ __forceinline__ u32 pack2(float a, float b) {
  return (u32)f2bf(a) | ((u32)f2bf(b) << 16);
}
__device__ __forceinline__ bf16x8 ld8(const u16* p) {
  return __builtin_bit_cast(bf16x8, *(const u32x4*)p);
}
__device__ __forceinline__ f32x4 mfma16(bf16x8 a, bf16x8 b, f32x4 c) {
  return __builtin_amdgcn_mfma_f32_16x16x32_bf16(a, b, c, 0, 0, 0);
}

// ---------------- k0: weight fragment tables ----------------
// wmg: [cb(32)][ks(2)][lane(64)][t(8)]  c=cb*16+(lane&15), k=ks*32+(lane>>4)*8+t
// wof: [cb(4)][ks(8)][lane(64)][t(8)]   c=cb*16+(lane&15), hk=ks*32+(lane>>4)*8+t
__global__ __launch_bounds__(256) void k0_prep(
    const float* __restrict__ Wm, const float* __restrict__ Wg,
    const float* __restrict__ Wo, u16* __restrict__ wmg, u16* __restrict__ wof) {
  const int idx = blockIdx.x * 256 + threadIdx.x;
  if (idx < 32768) {
    const int t = idx & 7, lane = (idx >> 3) & 63, ks = (idx >> 9) & 1, cb = idx >> 10;
    const int c = cb * 16 + (lane & 15);
    const int k = ks * 32 + ((lane >> 4) & 3) * 8 + t;
    const float v = (c < HK) ? Wm[k * HK + c] : Wg[k * HK + (c - HK)];
    wmg[idx] = f2bf(v);
  } else if (idx < 32768 + 16384) {
    const int j = idx - 32768;
    const int t = j & 7, lane = (j >> 3) & 63, ks = (j >> 9) & 7, cb = j >> 12;
    const int c = cb * 16 + (lane & 15);
    const int hk = ks * 32 + ((lane >> 4) & 3) * 8 + t;
    wof[j] = f2bf(Wo[hk * DM + c]);
  }
}

// ---------------- k1: LN(z) + pair bias + row softmax -> w bf16 ----------------
__global__ __launch_bounds__(256) void k1_softmax_w(
    const float* __restrict__ z, const float* __restrict__ znw,
    const float* __restrict__ znb, const float* __restrict__ Wz,
    u16* __restrict__ wout) {
  __shared__ float sWz[DZ][NH];
  __shared__ float swt[DZ], sbs[DZ];
  __shared__ float sB[NH][N_DIM];
  __shared__ float red[4];
  const int tid = threadIdx.x;
  const int i = blockIdx.x;
  if (tid < DZ) { swt[tid] = znw[tid]; sbs[tid] = znb[tid]; }
  for (int idx = tid; idx < DZ * NH; idx += 256) sWz[idx >> 3][idx & 7] = Wz[idx];
  __syncthreads();

  #pragma unroll
  for (int jj = 0; jj < 2; ++jj) {
    const int j = tid + jj * 256;
    const float4* zp = (const float4*)(z + ((size_t)i * N_DIM + j) * DZ);
    float sum = 0.f, sq = 0.f;
    for (int cc = 0; cc < DZ / 4; ++cc) {
      float4 v = zp[cc];
      sum += v.x + v.y + v.z + v.w;
      sq  += v.x * v.x + v.y * v.y + v.z * v.z + v.w * v.w;
    }
    const float mu = sum * (1.f / DZ);
    const float rs = rsqrtf(sq * (1.f / DZ) - mu * mu + 1e-5f);
    float acc[8] = {0.f, 0.f, 0.f, 0.f, 0.f, 0.f, 0.f, 0.f};
    for (int cc = 0; cc < DZ / 4; ++cc) {
      float4 v = zp[cc];
      #pragma unroll
      for (int e = 0; e < 4; ++e) {
        const int c = cc * 4 + e;
        const float x = (e == 0) ? v.x : (e == 1) ? v.y : (e == 2) ? v.z : v.w;
        const float zn = (x - mu) * rs * swt[c] + sbs[c];
        const float4 wa = ((const float4*)&sWz[c][0])[0];
        const float4 wb = ((const float4*)&sWz[c][0])[1];
        acc[0] += zn * wa.x; acc[1] += zn * wa.y; acc[2] += zn * wa.z; acc[3] += zn * wa.w;
        acc[4] += zn * wb.x; acc[5] += zn * wb.y; acc[6] += zn * wb.z; acc[7] += zn * wb.w;
      }
    }
    #pragma unroll
    for (int h = 0; h < NH; ++h) sB[h][j] = acc[h];
  }
  __syncthreads();

  for (int h = 0; h < NH; ++h) {
    const float v0 = sB[h][tid], v1 = sB[h][tid + 256];
    float mx = fmaxf(v0, v1);
    #pragma unroll
    for (int off = 32; off; off >>= 1) mx = fmaxf(mx, __shfl_xor(mx, off, 64));
    if ((tid & 63) == 0) red[tid >> 6] = mx;
    __syncthreads();
    mx = fmaxf(fmaxf(red[0], red[1]), fmaxf(red[2], red[3]));
    __syncthreads();
    const float e0 = __expf(v0 - mx), e1 = __expf(v1 - mx);
    float sm = e0 + e1;
    #pragma unroll
    for (int off = 32; off; off >>= 1) sm += __shfl_xor(sm, off, 64);
    if ((tid & 63) == 0) red[tid >> 6] = sm;
    __syncthreads();
    const float inv = 1.f / (red[0] + red[1] + red[2] + red[3]);
    u16* wp = wout + ((size_t)h * N_DIM + i) * N_DIM;
    wp[tid] = f2bf(e0 * inv);
    wp[tid + 256] = f2bf(e1 * inv);
    __syncthreads();
  }
}

// ---------------- k2a: LN(m) -> mn bf16 [r=(s,n)][64] ----------------
__global__ __launch_bounds__(256) void k2a_ln_m(
    const float* __restrict__ m, const float* __restrict__ mnw,
    const float* __restrict__ mnb, u16* __restrict__ mn) {
  __shared__ float sw[DM], sb[DM];
  const int tid = threadIdx.x;
  if (tid < DM) { sw[tid] = mnw[tid]; sb[tid] = mnb[tid]; }
  __syncthreads();
  const size_t r = (size_t)blockIdx.x * 256 + tid;
  const float4* mp = (const float4*)(m + r * DM);
  float4 arr[16];
  float sum = 0.f, sq = 0.f;
  #pragma unroll
  for (int q = 0; q < 16; ++q) {
    float4 v = mp[q]; arr[q] = v;
    sum += v.x + v.y + v.z + v.w;
    sq  += v.x * v.x + v.y * v.y + v.z * v.z + v.w * v.w;
  }
  const float mu = sum * (1.f / DM);
  const float rs = rsqrtf(sq * (1.f / DM) - mu * mu + 1e-5f);
  uint4* op = (uint4*)(mn + r * DM);
  #pragma unroll
  for (int q = 0; q < 8; ++q) {
    const float4 a = arr[2 * q], b = arr[2 * q + 1];
    const int c0 = q * 8;
    const float y0 = (a.x - mu) * rs * sw[c0 + 0] + sb[c0 + 0];
    const float y1 = (a.y - mu) * rs * sw[c0 + 1] + sb[c0 + 1];
    const float y2 = (a.z - mu) * rs * sw[c0 + 2] + sb[c0 + 2];
    const float y3 = (a.w - mu) * rs * sw[c0 + 3] + sb[c0 + 3];
    const float y4 = (b.x - mu) * rs * sw[c0 + 4] + sb[c0 + 4];
    const float y5 = (b.y - mu) * rs * sw[c0 + 5] + sb[c0 + 5];
    const float y6 = (b.z - mu) * rs * sw[c0 + 6] + sb[c0 + 6];
    const float y7 = (b.w - mu) * rs * sw[c0 + 7] + sb[c0 + 7];
    uint4 u;
    u.x = pack2(y0, y1); u.y = pack2(y2, y3);
    u.z = pack2(y4, y5); u.w = pack2(y6, y7);
    op[q] = u;
  }
}

// ---------------- k2b: v,g = mn @ [Wm|Wg]; MFMA, wave = 16 rows x 512 cols ----
// Vf layout: [h][jb=j>>5][cb=np>>4][lane2=((j>>3)&3)*16+(np&15)][t2=j&7], np=s*32+k
// g2 layout: [h][j][s*32+k]
__global__ __launch_bounds__(256) void k2b_proj(
    const u16* __restrict__ mn, const u16* __restrict__ wmg,
    u16* __restrict__ vf, u16* __restrict__ g2) {
  const int tid = threadIdx.x, lane = tid & 63, wv = tid >> 6;
  const int rbase = (blockIdx.x * 4 + wv) * 16;
  const u16* ap = mn + (size_t)(rbase + (lane & 15)) * DM + ((lane >> 4) & 3) * 8;
  const bf16x8 a0 = ld8(ap);
  const bf16x8 a1 = ld8(ap + 32);
  const u16* bp = wmg + lane * 8;
  const int r0 = rbase + ((lane >> 4) & 3) * 4;
  const int s0 = r0 >> 9;
  const int j0 = r0 & 511;

  {  // v half: c in [0,256)
    f32x4 acc[16];
    #pragma unroll
    for (int cb = 0; cb < 16; ++cb) acc[cb] = (f32x4){0.f, 0.f, 0.f, 0.f};
    #pragma unroll
    for (int cb = 0; cb < 16; ++cb) {
      acc[cb] = mfma16(a0, ld8(bp + cb * 1024), acc[cb]);
      acc[cb] = mfma16(a1, ld8(bp + cb * 1024 + 512), acc[cb]);
    }
    #pragma unroll
    for (int cb = 0; cb < 16; ++cb) {
      const int c = cb * 16 + (lane & 15);
      const int h = c >> 5, k = c & 31;
      const int np = s0 * HD + k;
      const size_t idx = (((size_t)(h * 16 + (j0 >> 5)) * 512 + (np >> 4)) * 64
                          + (((j0 >> 3) & 3) * 16 + (np & 15))) * 8 + (j0 & 7);
      ushort4 pk;
      pk.x = f2bf(acc[cb][0]); pk.y = f2bf(acc[cb][1]);
      pk.z = f2bf(acc[cb][2]); pk.w = f2bf(acc[cb][3]);
      *(ushort4*)(vf + idx) = pk;
    }
  }
  {  // g half: c in [256,512)
    f32x4 acc[16];
    #pragma unroll
    for (int cb = 0; cb < 16; ++cb) acc[cb] = (f32x4){0.f, 0.f, 0.f, 0.f};
    #pragma unroll
    for (int cb = 0; cb < 16; ++cb) {
      acc[cb] = mfma16(a0, ld8(bp + (cb + 16) * 1024), acc[cb]);
      acc[cb] = mfma16(a1, ld8(bp + (cb + 16) * 1024 + 512), acc[cb]);
    }
    #pragma unroll
    for (int cb = 0; cb < 16; ++cb) {
      const int cg = cb * 16 + (lane & 15);
      const int h = cg >> 5, k = cg & 31;
      #pragma unroll
      for (int rg = 0; rg < 4; ++rg) {
        const int j = j0 + rg;
        const float gv = 1.f / (1.f + __expf(-acc[cb][rg]));
        g2[((size_t)h * N_DIM + j) * NP + s0 * HD + k] = f2bf(gv);
      }
    }
  }
}

// ---------------- k3: per-head o = w @ v, gate in place over g2 ----------------
// grid dim3(8 h, 4 i-tiles, 64 n'-tiles): x-major dispatch -> XCD k owns head k,
// and the 4 i-tiles sharing a v-panel run consecutively on that XCD (L2-hot).
__global__ __launch_bounds__(256) void k3_pwa(
    const u16* __restrict__ wb, const u16* __restrict__ vf, u16* __restrict__ g2) {
  const int tid = threadIdx.x, lane = tid & 63, wv = tid >> 6;
  const int wr = wv >> 1, wc = wv & 1;
  const int h = blockIdx.x;
  const int i0 = blockIdx.y * 128 + wr * 64;
  const int n0 = blockIdx.z * 128 + wc * 64;
  f32x4 acc[4][4];
  #pragma unroll
  for (int a = 0; a < 4; ++a)
    #pragma unroll
    for (int b = 0; b < 4; ++b) acc[a][b] = (f32x4){0.f, 0.f, 0.f, 0.f};

  const u16* ap = wb + ((size_t)h * N_DIM + i0 + (lane & 15)) * N_DIM + ((lane >> 4) & 3) * 8;
  const u16* bp = vf + (size_t)h * 4194304 + ((size_t)(n0 >> 4) * 64 + lane) * 8;

  bf16x8 ac[4], bc[4];
  #pragma unroll
  for (int fm = 0; fm < 4; ++fm) ac[fm] = ld8(ap + fm * 8192);
  #pragma unroll
  for (int fn = 0; fn < 4; ++fn) bc[fn] = ld8(bp + fn * 512);

  for (int kt = 0; kt < 16; ++kt) {
    const int ktn = (kt + 1) & 15;  // wrap: last-iter prefetch is harmless reload
    bf16x8 an[4], bn[4];
    #pragma unroll
    for (int fm = 0; fm < 4; ++fm) an[fm] = ld8(ap + ktn * 32 + fm * 8192);
    #pragma unroll
    for (int fn = 0; fn < 4; ++fn) bn[fn] = ld8(bp + (size_t)ktn * 262144 + fn * 512);
    #pragma unroll
    for (int fm = 0; fm < 4; ++fm)
      #pragma unroll
      for (int fn = 0; fn < 4; ++fn)
        acc[fm][fn] = mfma16(ac[fm], bc[fn], acc[fm][fn]);
    #pragma unroll
    for (int fm = 0; fm < 4; ++fm) ac[fm] = an[fm];
    #pragma unroll
    for (int fn = 0; fn < 4; ++fn) bc[fn] = bn[fn];
  }

  #pragma unroll
  for (int fm = 0; fm < 4; ++fm) {
    #pragma unroll
    for (int fn = 0; fn < 4; ++fn) {
      #pragma unroll
      for (int rg = 0; rg < 4; ++rg) {
        const int i = i0 + fm * 16 + ((lane >> 4) & 3) * 4 + rg;
        const int np = n0 + fn * 16 + (lane & 15);
        const size_t idx = ((size_t)h * N_DIM + i) * NP + np;
        const float gv = bf2f(g2[idx]);
        g2[idx] = f2bf(acc[fm][fn][rg] * gv);  // og overwrites g2 in place
      }
    }
  }
}

// ---------------- k4: out = og @ Wo (f32 out) ----------------
__global__ __launch_bounds__(256) void k4_out(
    const u16* __restrict__ og, const u16* __restrict__ wof,
    float* __restrict__ out) {
  const int tid = threadIdx.x, lane = tid & 63, wv = tid >> 6;
  const int rbase = (blockIdx.x * 4 + wv) * 16;
  const int rl = rbase + (lane & 15);
  const int s = rl >> 9, i = rl & 511;
  const u16* ap = og + (size_t)i * NP + s * HD + ((lane >> 4) & 3) * 8;
  const u16* bp = wof + lane * 8;
  f32x4 acc[4];
  #pragma unroll
  for (int fn = 0; fn < 4; ++fn) acc[fn] = (f32x4){0.f, 0.f, 0.f, 0.f};
  #pragma unroll
  for (int ks = 0; ks < 8; ++ks) {  // ks == head
    const bf16x8 a = ld8(ap + (size_t)ks * 4194304);
    #pragma unroll
    for (int fn = 0; fn < 4; ++fn)
      acc[fn] = mfma16(a, ld8(bp + (fn * 8 + ks) * 512), acc[fn]);
  }
  const int r0 = rbase + ((lane >> 4) & 3) * 4;
  #pragma unroll
  for (int fn = 0; fn < 4; ++fn)
    #pragma unroll
    for (int rg = 0; rg < 4; ++rg)
      out[(size_t)(r0 + rg) * DM + fn * 16 + (lane & 15)] = acc[fn][rg];
}

extern "C" void kernel_launch(void* const* d_in, const int* in_sizes, int n_in,
                              void* d_out, int out_size, void* d_ws, size_t ws_size,
                              hipStream_t stream) {
  const float* m   = (const float*)d_in[0];
  const float* z   = (const float*)d_in[1];
  const float* mnw = (const float*)d_in[2];
  const float* mnb = (const float*)d_in[3];
  const float* znw = (const float*)d_in[4];
  const float* znb = (const float*)d_in[5];
  const float* Wm  = (const float*)d_in[6];
  const float* Wg  = (const float*)d_in[7];
  const float* Wz  = (const float*)d_in[8];
  const float* Wo  = (const float*)d_in[9];
  float* out = (float*)d_out;
  char* ws = (char*)d_ws;

  // ws layout (bytes): w 4MiB | Vf 64MiB | g2 64MiB | mn 16MiB | wmg 64KiB | wof 32KiB
  u16* wbuf = (u16*)(ws);
  u16* vf   = (u16*)(ws + ((size_t)4   << 20));
  u16* g2   = (u16*)(ws + ((size_t)68  << 20));
  u16* mn   = (u16*)(ws + ((size_t)132 << 20));
  u16* wmg  = (u16*)(ws + ((size_t)148 << 20));
  u16* wof  = (u16*)(ws + ((size_t)148 << 20) + 65536);

  k0_prep<<<192, 256, 0, stream>>>(Wm, Wg, Wo, wmg, wof);
  k1_softmax_w<<<512, 256, 0, stream>>>(z, znw, znb, Wz, wbuf);
  k2a_ln_m<<<512, 256, 0, stream>>>(m, mnw, mnb, mn);
  k2b_proj<<<2048, 256, 0, stream>>>(mn, wmg, vf, g2);
  k3_pwa<<<dim3(8, 4, 64), 256, 0, stream>>>(wbuf, vf, g2);
  k4_out<<<2048, 256, 0, stream>>>(g2, wof, out);
}

// Round 2
// 249.723 us; speedup vs baseline: 1.0402x; 1.0402x over previous
//
#include <hip/hip_runtime.h>

// PairWeightedAveraging: m[1,S,N,Dm], z[1,N,N,Dz] -> out[1,S,N,Dm]
// S=256 N=512 Dm=64 Dz=128 H=8 HD=32
// Pipeline (all bf16 MFMA):
//  k0: pre-swizzle [Wm|Wg] and Wo into per-lane fragment tables
//  k1: LN(z) + b=zn*Wz + softmax_j -> wf[h][jt][i][32] bf16 (K-panel layout)
//  k2a: LN(m) -> mn bf16
//  k2b: v,g = mn @ [Wm|Wg]; v -> vf[h][jt][np][32], g=sigmoid -> g2[h][i][np]
//  k3: per-head GEMM o = w @ v (m97-style LDS double-buffered, global_load_lds,
//      XOR-swizzled panels), gate with g2 IN-PLACE (og overwrites g2)
//  k4: out = og @ Wo (og layout is already A-fragment-native)

#define S_DIM 256
#define N_DIM 512
#define DM 64
#define DZ 128
#define NH 8
#define HD 32
#define HK 256
#define NP 8192  // S_DIM*HD
#define BKP 32   // k3 K-panel depth
#define JT_N 16  // 512 / BKP

typedef unsigned int   u32;
typedef unsigned short u16;
typedef __bf16 bf16x8 __attribute__((ext_vector_type(8)));
typedef float  f32x4  __attribute__((ext_vector_type(4)));
typedef u32    u32x4  __attribute__((ext_vector_type(4)));

__device__ __forceinline__ u16 f2bf(float f) {
  u32 u = __builtin_bit_cast(u32, f);
  return (u16)((u + 0x7FFFu + ((u >> 16) & 1u)) >> 16);  // RNE
}
__device__ __forceinline__ float bf2f(u16 h) {
  u32 u = ((u32)h) << 16;
  return __builtin_bit_cast(float, u);
}
__device__ __forceinline__ u32 pack2(float a, float b) {
  return (u32)f2bf(a) | ((u32)f2bf(b) << 16);
}
__device__ __forceinline__ bf16x8 ld8(const u16* p) {
  return __builtin_bit_cast(bf16x8, *(const u32x4*)p);
}
__device__ __forceinline__ f32x4 mfma16(bf16x8 a, bf16x8 b, f32x4 c) {
  return __builtin_amdgcn_mfma_f32_16x16x32_bf16(a, b, c, 0, 0, 0);
}
__device__ __forceinline__ void gload_lds16(const void* gsrc, void* ldst) {
  __builtin_amdgcn_global_load_lds(
      (const __attribute__((address_space(1))) void*)gsrc,
      (__attribute__((address_space(3))) void*)ldst, 16, 0, 0);
}
// panel byte-offset swizzle (involution; permutes 16B chunks within 8 rows of 64B)
__device__ __forceinline__ int swz(int lin) { return lin ^ (((lin >> 7) & 3) << 4); }

// ---------------- k0: weight fragment tables ----------------
// wmg: [cb(32)][ks(2)][lane(64)][t(8)]  c=cb*16+(lane&15), k=ks*32+(lane>>4)*8+t
// wof: [cb(4)][ks(8)][lane(64)][t(8)]   c=cb*16+(lane&15), hk=ks*32+(lane>>4)*8+t
__global__ __launch_bounds__(256) void k0_prep(
    const float* __restrict__ Wm, const float* __restrict__ Wg,
    const float* __restrict__ Wo, u16* __restrict__ wmg, u16* __restrict__ wof) {
  const int idx = blockIdx.x * 256 + threadIdx.x;
  if (idx < 32768) {
    const int t = idx & 7, lane = (idx >> 3) & 63, ks = (idx >> 9) & 1, cb = idx >> 10;
    const int c = cb * 16 + (lane & 15);
    const int k = ks * 32 + ((lane >> 4) & 3) * 8 + t;
    const float v = (c < HK) ? Wm[k * HK + c] : Wg[k * HK + (c - HK)];
    wmg[idx] = f2bf(v);
  } else if (idx < 32768 + 16384) {
    const int j = idx - 32768;
    const int t = j & 7, lane = (j >> 3) & 63, ks = (j >> 9) & 7, cb = j >> 12;
    const int c = cb * 16 + (lane & 15);
    const int hk = ks * 32 + ((lane >> 4) & 3) * 8 + t;
    wof[j] = f2bf(Wo[hk * DM + c]);
  }
}

// ---------------- k1: LN(z) + pair bias + row softmax -> wf bf16 ----------------
// wf layout: [h][jt=j>>5][i][j&31]
__global__ __launch_bounds__(256) void k1_softmax_w(
    const float* __restrict__ z, const float* __restrict__ znw,
    const float* __restrict__ znb, const float* __restrict__ Wz,
    u16* __restrict__ wout) {
  __shared__ float sWz[DZ][NH];
  __shared__ float swt[DZ], sbs[DZ];
  __shared__ float sB[NH][N_DIM];
  __shared__ float red[4];
  const int tid = threadIdx.x;
  const int i = blockIdx.x;
  if (tid < DZ) { swt[tid] = znw[tid]; sbs[tid] = znb[tid]; }
  for (int idx = tid; idx < DZ * NH; idx += 256) sWz[idx >> 3][idx & 7] = Wz[idx];
  __syncthreads();

  #pragma unroll
  for (int jj = 0; jj < 2; ++jj) {
    const int j = tid + jj * 256;
    const float4* zp = (const float4*)(z + ((size_t)i * N_DIM + j) * DZ);
    float sum = 0.f, sq = 0.f;
    for (int cc = 0; cc < DZ / 4; ++cc) {
      float4 v = zp[cc];
      sum += v.x + v.y + v.z + v.w;
      sq  += v.x * v.x + v.y * v.y + v.z * v.z + v.w * v.w;
    }
    const float mu = sum * (1.f / DZ);
    const float rs = rsqrtf(sq * (1.f / DZ) - mu * mu + 1e-5f);
    float acc[8] = {0.f, 0.f, 0.f, 0.f, 0.f, 0.f, 0.f, 0.f};
    for (int cc = 0; cc < DZ / 4; ++cc) {
      float4 v = zp[cc];
      #pragma unroll
      for (int e = 0; e < 4; ++e) {
        const int c = cc * 4 + e;
        const float x = (e == 0) ? v.x : (e == 1) ? v.y : (e == 2) ? v.z : v.w;
        const float zn = (x - mu) * rs * swt[c] + sbs[c];
        const float4 wa = ((const float4*)&sWz[c][0])[0];
        const float4 wb = ((const float4*)&sWz[c][0])[1];
        acc[0] += zn * wa.x; acc[1] += zn * wa.y; acc[2] += zn * wa.z; acc[3] += zn * wa.w;
        acc[4] += zn * wb.x; acc[5] += zn * wb.y; acc[6] += zn * wb.z; acc[7] += zn * wb.w;
      }
    }
    #pragma unroll
    for (int h = 0; h < NH; ++h) sB[h][j] = acc[h];
  }
  __syncthreads();

  for (int h = 0; h < NH; ++h) {
    const float v0 = sB[h][tid], v1 = sB[h][tid + 256];
    float mx = fmaxf(v0, v1);
    #pragma unroll
    for (int off = 32; off; off >>= 1) mx = fmaxf(mx, __shfl_xor(mx, off, 64));
    if ((tid & 63) == 0) red[tid >> 6] = mx;
    __syncthreads();
    mx = fmaxf(fmaxf(red[0], red[1]), fmaxf(red[2], red[3]));
    __syncthreads();
    const float e0 = __expf(v0 - mx), e1 = __expf(v1 - mx);
    float sm = e0 + e1;
    #pragma unroll
    for (int off = 32; off; off >>= 1) sm += __shfl_xor(sm, off, 64);
    if ((tid & 63) == 0) red[tid >> 6] = sm;
    __syncthreads();
    const float inv = 1.f / (red[0] + red[1] + red[2] + red[3]);
    const int j0 = tid, j1 = tid + 256;
    wout[(((size_t)(h * JT_N + (j0 >> 5)) * N_DIM + i) << 5) + (j0 & 31)] = f2bf(e0 * inv);
    wout[(((size_t)(h * JT_N + (j1 >> 5)) * N_DIM + i) << 5) + (j1 & 31)] = f2bf(e1 * inv);
    __syncthreads();
  }
}

// ---------------- k2a: LN(m) -> mn bf16 [r=(s,n)][64] ----------------
__global__ __launch_bounds__(256) void k2a_ln_m(
    const float* __restrict__ m, const float* __restrict__ mnw,
    const float* __restrict__ mnb, u16* __restrict__ mn) {
  __shared__ float sw[DM], sb[DM];
  const int tid = threadIdx.x;
  if (tid < DM) { sw[tid] = mnw[tid]; sb[tid] = mnb[tid]; }
  __syncthreads();
  const size_t r = (size_t)blockIdx.x * 256 + tid;
  const float4* mp = (const float4*)(m + r * DM);
  float4 arr[16];
  float sum = 0.f, sq = 0.f;
  #pragma unroll
  for (int q = 0; q < 16; ++q) {
    float4 v = mp[q]; arr[q] = v;
    sum += v.x + v.y + v.z + v.w;
    sq  += v.x * v.x + v.y * v.y + v.z * v.z + v.w * v.w;
  }
  const float mu = sum * (1.f / DM);
  const float rs = rsqrtf(sq * (1.f / DM) - mu * mu + 1e-5f);
  uint4* op = (uint4*)(mn + r * DM);
  #pragma unroll
  for (int q = 0; q < 8; ++q) {
    const float4 a = arr[2 * q], b = arr[2 * q + 1];
    const int c0 = q * 8;
    const float y0 = (a.x - mu) * rs * sw[c0 + 0] + sb[c0 + 0];
    const float y1 = (a.y - mu) * rs * sw[c0 + 1] + sb[c0 + 1];
    const float y2 = (a.z - mu) * rs * sw[c0 + 2] + sb[c0 + 2];
    const float y3 = (a.w - mu) * rs * sw[c0 + 3] + sb[c0 + 3];
    const float y4 = (b.x - mu) * rs * sw[c0 + 4] + sb[c0 + 4];
    const float y5 = (b.y - mu) * rs * sw[c0 + 5] + sb[c0 + 5];
    const float y6 = (b.z - mu) * rs * sw[c0 + 6] + sb[c0 + 6];
    const float y7 = (b.w - mu) * rs * sw[c0 + 7] + sb[c0 + 7];
    uint4 u;
    u.x = pack2(y0, y1); u.y = pack2(y2, y3);
    u.z = pack2(y4, y5); u.w = pack2(y6, y7);
    op[q] = u;
  }
}

// ---------------- k2b: v,g = mn @ [Wm|Wg]; MFMA, wave = 16 rows x 512 cols ----
// vf layout: [h][jt=j>>5][np][j&31], np=s*32+k
// g2 layout: [h][j][s*32+k]
__global__ __launch_bounds__(256) void k2b_proj(
    const u16* __restrict__ mn, const u16* __restrict__ wmg,
    u16* __restrict__ vf, u16* __restrict__ g2) {
  const int tid = threadIdx.x, lane = tid & 63, wv = tid >> 6;
  const int rbase = (blockIdx.x * 4 + wv) * 16;
  const u16* ap = mn + (size_t)(rbase + (lane & 15)) * DM + ((lane >> 4) & 3) * 8;
  const bf16x8 a0 = ld8(ap);
  const bf16x8 a1 = ld8(ap + 32);
  const u16* bp = wmg + lane * 8;
  const int r0 = rbase + ((lane >> 4) & 3) * 4;
  const int s0 = r0 >> 9;
  const int j0 = r0 & 511;

  {  // v half: c in [0,256)
    f32x4 acc[16];
    #pragma unroll
    for (int cb = 0; cb < 16; ++cb) acc[cb] = (f32x4){0.f, 0.f, 0.f, 0.f};
    #pragma unroll
    for (int cb = 0; cb < 16; ++cb) {
      acc[cb] = mfma16(a0, ld8(bp + cb * 1024), acc[cb]);
      acc[cb] = mfma16(a1, ld8(bp + cb * 1024 + 512), acc[cb]);
    }
    #pragma unroll
    for (int cb = 0; cb < 16; ++cb) {
      const int c = cb * 16 + (lane & 15);
      const int h = c >> 5, k = c & 31;
      const int np = s0 * HD + k;
      const size_t idx = (((size_t)(h * JT_N + (j0 >> 5)) * NP + np) << 5) + (j0 & 31);
      ushort4 pk;
      pk.x = f2bf(acc[cb][0]); pk.y = f2bf(acc[cb][1]);
      pk.z = f2bf(acc[cb][2]); pk.w = f2bf(acc[cb][3]);
      *(ushort4*)(vf + idx) = pk;
    }
  }
  {  // g half: c in [256,512)
    f32x4 acc[16];
    #pragma unroll
    for (int cb = 0; cb < 16; ++cb) acc[cb] = (f32x4){0.f, 0.f, 0.f, 0.f};
    #pragma unroll
    for (int cb = 0; cb < 16; ++cb) {
      acc[cb] = mfma16(a0, ld8(bp + (cb + 16) * 1024), acc[cb]);
      acc[cb] = mfma16(a1, ld8(bp + (cb + 16) * 1024 + 512), acc[cb]);
    }
    #pragma unroll
    for (int cb = 0; cb < 16; ++cb) {
      const int cg = cb * 16 + (lane & 15);
      const int h = cg >> 5, k = cg & 31;
      #pragma unroll
      for (int rg = 0; rg < 4; ++rg) {
        const int j = j0 + rg;
        const float gv = 1.f / (1.f + __expf(-acc[cb][rg]));
        g2[((size_t)h * N_DIM + j) * NP + s0 * HD + k] = f2bf(gv);
      }
    }
  }
}

// ---------------- k3: per-head o = w @ v, m97-style LDS dbuf GEMM ----------------
// grid dim3(8 h, 4 i-tiles, 64 n'-tiles): XCD k owns head k (idx%8==x).
// Block tile 128x128, BK=32, 4 waves each 64x64 (4x4 16x16 frags).
// LDS panels 8KB each, staged via global_load_lds w/ XOR swizzle (G21 both-sides).
__global__ __launch_bounds__(256) void k3_pwa(
    const u16* __restrict__ wf, const u16* __restrict__ vf, u16* __restrict__ g2) {
  __shared__ __attribute__((aligned(16))) u16 lA[2][128 * BKP];
  __shared__ __attribute__((aligned(16))) u16 lB[2][128 * BKP];
  const int tid = threadIdx.x, lane = tid & 63, wv = tid >> 6;
  const int wr = wv >> 1, wc = wv & 1;
  const int h = blockIdx.x;
  const int i0 = blockIdx.y * 128;
  const int n0 = blockIdx.z * 128;

  // global K-panel bases (each panel = 128 rows x 32 u16 = 8KB contiguous)
  const char* gA = (const char*)(wf + (((size_t)h * JT_N * N_DIM) + i0) * BKP);
  const char* gB = (const char*)(vf + (((size_t)h * JT_N * NP) + n0) * BKP);

  // per-wave stage: wave wv covers panel bytes [wv*2048, wv*2048+2048) of A and B
  const int sbase0 = wv * 2048;
  const int sbase1 = wv * 2048 + 1024;
  const int soff0 = swz(sbase0 + lane * 16);
  const int soff1 = swz(sbase1 + lane * 16);

  f32x4 acc[4][4];
  #pragma unroll
  for (int a = 0; a < 4; ++a)
    #pragma unroll
    for (int b = 0; b < 4; ++b) acc[a][b] = (f32x4){0.f, 0.f, 0.f, 0.f};

  // swizzled LDS read offsets (bytes within panel)
  int offA[4], offB[4];
  #pragma unroll
  for (int f = 0; f < 4; ++f) {
    const int ra = wr * 64 + f * 16 + (lane & 15);
    const int rb = wc * 64 + f * 16 + (lane & 15);
    offA[f] = swz(ra * 64 + ((lane >> 4) & 3) * 16);
    offB[f] = swz(rb * 64 + ((lane >> 4) & 3) * 16);
  }

  // prologue: stage jt=0 into buf 0
  {
    const char* pA = gA;  // jt=0
    const char* pB = gB;
    gload_lds16(pA + soff0, (char*)&lA[0][0] + sbase0);
    gload_lds16(pA + soff1, (char*)&lA[0][0] + sbase1);
    gload_lds16(pB + soff0, (char*)&lB[0][0] + sbase0);
    gload_lds16(pB + soff1, (char*)&lB[0][0] + sbase1);
  }
  __syncthreads();

  int cur = 0;
  for (int jt = 0; jt < JT_N; ++jt) {
    if (jt < JT_N - 1) {
      const char* pA = gA + (size_t)(jt + 1) * (N_DIM * BKP * 2);
      const char* pB = gB + (size_t)(jt + 1) * (NP * BKP * 2);
      gload_lds16(pA + soff0, (char*)&lA[cur ^ 1][0] + sbase0);
      gload_lds16(pA + soff1, (char*)&lA[cur ^ 1][0] + sbase1);
      gload_lds16(pB + soff0, (char*)&lB[cur ^ 1][0] + sbase0);
      gload_lds16(pB + soff1, (char*)&lB[cur ^ 1][0] + sbase1);
    }
    bf16x8 af[4], bf[4];
    #pragma unroll
    for (int f = 0; f < 4; ++f) af[f] = ld8((const u16*)((const char*)&lA[cur][0] + offA[f]));
    #pragma unroll
    for (int f = 0; f < 4; ++f) bf[f] = ld8((const u16*)((const char*)&lB[cur][0] + offB[f]));
    #pragma unroll
    for (int fm = 0; fm < 4; ++fm)
      #pragma unroll
      for (int fn = 0; fn < 4; ++fn)
        acc[fm][fn] = mfma16(af[fm], bf[fn], acc[fm][fn]);
    __syncthreads();
    cur ^= 1;
  }

  #pragma unroll
  for (int fm = 0; fm < 4; ++fm) {
    #pragma unroll
    for (int fn = 0; fn < 4; ++fn) {
      #pragma unroll
      for (int rg = 0; rg < 4; ++rg) {
        const int i = i0 + wr * 64 + fm * 16 + ((lane >> 4) & 3) * 4 + rg;
        const int np = n0 + wc * 64 + fn * 16 + (lane & 15);
        const size_t idx = ((size_t)h * N_DIM + i) * NP + np;
        const float gv = bf2f(g2[idx]);
        g2[idx] = f2bf(acc[fm][fn][rg] * gv);  // og overwrites g2 in place
      }
    }
  }
}

// ---------------- k4: out = og @ Wo (f32 out) ----------------
__global__ __launch_bounds__(256) void k4_out(
    const u16* __restrict__ og, const u16* __restrict__ wof,
    float* __restrict__ out) {
  const int tid = threadIdx.x, lane = tid & 63, wv = tid >> 6;
  const int rbase = (blockIdx.x * 4 + wv) * 16;
  const int rl = rbase + (lane & 15);
  const int s = rl >> 9, i = rl & 511;
  const u16* ap = og + (size_t)i * NP + s * HD + ((lane >> 4) & 3) * 8;
  const u16* bp = wof + lane * 8;
  f32x4 acc[4];
  #pragma unroll
  for (int fn = 0; fn < 4; ++fn) acc[fn] = (f32x4){0.f, 0.f, 0.f, 0.f};
  #pragma unroll
  for (int ks = 0; ks < 8; ++ks) {  // ks == head
    const bf16x8 a = ld8(ap + (size_t)ks * 4194304);
    #pragma unroll
    for (int fn = 0; fn < 4; ++fn)
      acc[fn] = mfma16(a, ld8(bp + (fn * 8 + ks) * 512), acc[fn]);
  }
  const int r0 = rbase + ((lane >> 4) & 3) * 4;
  #pragma unroll
  for (int fn = 0; fn < 4; ++fn)
    #pragma unroll
    for (int rg = 0; rg < 4; ++rg)
      out[(size_t)(r0 + rg) * DM + fn * 16 + (lane & 15)] = acc[fn][rg];
}

extern "C" void kernel_launch(void* const* d_in, const int* in_sizes, int n_in,
                              void* d_out, int out_size, void* d_ws, size_t ws_size,
                              hipStream_t stream) {
  const float* m   = (const float*)d_in[0];
  const float* z   = (const float*)d_in[1];
  const float* mnw = (const float*)d_in[2];
  const float* mnb = (const float*)d_in[3];
  const float* znw = (const float*)d_in[4];
  const float* znb = (const float*)d_in[5];
  const float* Wm  = (const float*)d_in[6];
  const float* Wg  = (const float*)d_in[7];
  const float* Wz  = (const float*)d_in[8];
  const float* Wo  = (const float*)d_in[9];
  float* out = (float*)d_out;
  char* ws = (char*)d_ws;

  // ws layout (bytes): wf 4MiB | vf 64MiB | g2 64MiB | mn 16MiB | wmg 64KiB | wof 32KiB
  u16* wbuf = (u16*)(ws);
  u16* vf   = (u16*)(ws + ((size_t)4   << 20));
  u16* g2   = (u16*)(ws + ((size_t)68  << 20));
  u16* mn   = (u16*)(ws + ((size_t)132 << 20));
  u16* wmg  = (u16*)(ws + ((size_t)148 << 20));
  u16* wof  = (u16*)(ws + ((size_t)148 << 20) + 65536);

  k0_prep<<<192, 256, 0, stream>>>(Wm, Wg, Wo, wmg, wof);
  k1_softmax_w<<<512, 256, 0, stream>>>(z, znw, znb, Wz, wbuf);
  k2a_ln_m<<<512, 256, 0, stream>>>(m, mnw, mnb, mn);
  k2b_proj<<<2048, 256, 0, stream>>>(mn, wmg, vf, g2);
  k3_pwa<<<dim3(8, 4, 64), 256, 0, stream>>>(wbuf, vf, g2);
  k4_out<<<2048, 256, 0, stream>>>(g2, wof, out);
}

// Round 3
// 232.377 us; speedup vs baseline: 1.1179x; 1.0746x over previous
//
#include <hip/hip_runtime.h>

// PairWeightedAveraging: m[1,S,N,Dm], z[1,N,N,Dz] -> out[1,S,N,Dm]
// S=256 N=512 Dm=64 Dz=128 H=8 HD=32
// Pipeline (all bf16 MFMA):
//  k0: pre-swizzle [Wm|Wg] and Wo into per-lane fragment tables
//  k1: LN(z) + b=zn*Wz + softmax_j -> wf[h][jt][i][32] bf16 (K-panel layout)
//  k2a: LN(m) -> mn bf16
//  k2b: v,g = mn @ [Wm|Wg]; v -> vf[h][jt][np][32]; g=sigmoid -> g2[h][j][np]
//       (g-half uses swapped-operand MFMA so stores are ushort4)
//  k3: per-head GEMM o = w @ v, counted-vmcnt 3-slot ring pipeline (never
//      vmcnt(0) in loop), swapped-operand MFMA -> vectorized g2 gate-RMW
//  k4: out = og @ Wo (og layout is A-fragment-native)

#define S_DIM 256
#define N_DIM 512
#define DM 64
#define DZ 128
#define NH 8
#define HD 32
#define HK 256
#define NP 8192  // S_DIM*HD
#define BKP 32   // k3 K-panel depth
#define JT_N 16  // 512 / BKP

typedef unsigned int   u32;
typedef unsigned short u16;
typedef __bf16 bf16x8 __attribute__((ext_vector_type(8)));
typedef float  f32x4  __attribute__((ext_vector_type(4)));
typedef u32    u32x4  __attribute__((ext_vector_type(4)));

__device__ __forceinline__ u16 f2bf(float f) {
  u32 u = __builtin_bit_cast(u32, f);
  return (u16)((u + 0x7FFFu + ((u >> 16) & 1u)) >> 16);  // RNE
}
__device__ __forceinline__ float bf2f(u16 h) {
  u32 u = ((u32)h) << 16;
  return __builtin_bit_cast(float, u);
}
__device__ __forceinline__ u32 pack2(float a, float b) {
  return (u32)f2bf(a) | ((u32)f2bf(b) << 16);
}
__device__ __forceinline__ bf16x8 ld8(const u16* p) {
  return __builtin_bit_cast(bf16x8, *(const u32x4*)p);
}
__device__ __forceinline__ f32x4 mfma16(bf16x8 a, bf16x8 b, f32x4 c) {
  return __builtin_amdgcn_mfma_f32_16x16x32_bf16(a, b, c, 0, 0, 0);
}
__device__ __forceinline__ void gload_lds16(const void* gsrc, void* ldst) {
  __builtin_amdgcn_global_load_lds(
      (const __attribute__((address_space(1))) void*)gsrc,
      (__attribute__((address_space(3))) void*)ldst, 16, 0, 0);
}
// panel byte-offset swizzle (involution; permutes 16B chunks within 8 rows of 64B)
__device__ __forceinline__ int swz(int lin) { return lin ^ (((lin >> 7) & 3) << 4); }

#define BARRIER() do { asm volatile("" ::: "memory"); \
                       __builtin_amdgcn_s_barrier();  \
                       asm volatile("" ::: "memory"); } while (0)

// ---------------- k0: weight fragment tables ----------------
// wmg: [cb(32)][ks(2)][lane(64)][t(8)]  c=cb*16+(lane&15), k=ks*32+(lane>>4)*8+t
// wof: [cb(4)][ks(8)][lane(64)][t(8)]   c=cb*16+(lane&15), hk=ks*32+(lane>>4)*8+t
__global__ __launch_bounds__(256) void k0_prep(
    const float* __restrict__ Wm, const float* __restrict__ Wg,
    const float* __restrict__ Wo, u16* __restrict__ wmg, u16* __restrict__ wof) {
  const int idx = blockIdx.x * 256 + threadIdx.x;
  if (idx < 32768) {
    const int t = idx & 7, lane = (idx >> 3) & 63, ks = (idx >> 9) & 1, cb = idx >> 10;
    const int c = cb * 16 + (lane & 15);
    const int k = ks * 32 + ((lane >> 4) & 3) * 8 + t;
    const float v = (c < HK) ? Wm[k * HK + c] : Wg[k * HK + (c - HK)];
    wmg[idx] = f2bf(v);
  } else if (idx < 32768 + 16384) {
    const int j = idx - 32768;
    const int t = j & 7, lane = (j >> 3) & 63, ks = (j >> 9) & 7, cb = j >> 12;
    const int c = cb * 16 + (lane & 15);
    const int hk = ks * 32 + ((lane >> 4) & 3) * 8 + t;
    wof[j] = f2bf(Wo[hk * DM + c]);
  }
}

// ---------------- k1: LN(z) + pair bias + row softmax -> wf bf16 ----------------
// wf layout: [h][jt=j>>5][i][j&31]
__global__ __launch_bounds__(256) void k1_softmax_w(
    const float* __restrict__ z, const float* __restrict__ znw,
    const float* __restrict__ znb, const float* __restrict__ Wz,
    u16* __restrict__ wout) {
  __shared__ float sWz[DZ][NH];
  __shared__ float swt[DZ], sbs[DZ];
  __shared__ float sB[NH][N_DIM];
  __shared__ float red[4];
  const int tid = threadIdx.x;
  const int i = blockIdx.x;
  if (tid < DZ) { swt[tid] = znw[tid]; sbs[tid] = znb[tid]; }
  for (int idx = tid; idx < DZ * NH; idx += 256) sWz[idx >> 3][idx & 7] = Wz[idx];
  __syncthreads();

  #pragma unroll
  for (int jj = 0; jj < 2; ++jj) {
    const int j = tid + jj * 256;
    const float4* zp = (const float4*)(z + ((size_t)i * N_DIM + j) * DZ);
    float sum = 0.f, sq = 0.f;
    for (int cc = 0; cc < DZ / 4; ++cc) {
      float4 v = zp[cc];
      sum += v.x + v.y + v.z + v.w;
      sq  += v.x * v.x + v.y * v.y + v.z * v.z + v.w * v.w;
    }
    const float mu = sum * (1.f / DZ);
    const float rs = rsqrtf(sq * (1.f / DZ) - mu * mu + 1e-5f);
    float acc[8] = {0.f, 0.f, 0.f, 0.f, 0.f, 0.f, 0.f, 0.f};
    for (int cc = 0; cc < DZ / 4; ++cc) {
      float4 v = zp[cc];
      #pragma unroll
      for (int e = 0; e < 4; ++e) {
        const int c = cc * 4 + e;
        const float x = (e == 0) ? v.x : (e == 1) ? v.y : (e == 2) ? v.z : v.w;
        const float zn = (x - mu) * rs * swt[c] + sbs[c];
        const float4 wa = ((const float4*)&sWz[c][0])[0];
        const float4 wb = ((const float4*)&sWz[c][0])[1];
        acc[0] += zn * wa.x; acc[1] += zn * wa.y; acc[2] += zn * wa.z; acc[3] += zn * wa.w;
        acc[4] += zn * wb.x; acc[5] += zn * wb.y; acc[6] += zn * wb.z; acc[7] += zn * wb.w;
      }
    }
    #pragma unroll
    for (int h = 0; h < NH; ++h) sB[h][j] = acc[h];
  }
  __syncthreads();

  for (int h = 0; h < NH; ++h) {
    const float v0 = sB[h][tid], v1 = sB[h][tid + 256];
    float mx = fmaxf(v0, v1);
    #pragma unroll
    for (int off = 32; off; off >>= 1) mx = fmaxf(mx, __shfl_xor(mx, off, 64));
    if ((tid & 63) == 0) red[tid >> 6] = mx;
    __syncthreads();
    mx = fmaxf(fmaxf(red[0], red[1]), fmaxf(red[2], red[3]));
    __syncthreads();
    const float e0 = __expf(v0 - mx), e1 = __expf(v1 - mx);
    float sm = e0 + e1;
    #pragma unroll
    for (int off = 32; off; off >>= 1) sm += __shfl_xor(sm, off, 64);
    if ((tid & 63) == 0) red[tid >> 6] = sm;
    __syncthreads();
    const float inv = 1.f / (red[0] + red[1] + red[2] + red[3]);
    const int j0 = tid, j1 = tid + 256;
    wout[(((size_t)(h * JT_N + (j0 >> 5)) * N_DIM + i) << 5) + (j0 & 31)] = f2bf(e0 * inv);
    wout[(((size_t)(h * JT_N + (j1 >> 5)) * N_DIM + i) << 5) + (j1 & 31)] = f2bf(e1 * inv);
    __syncthreads();
  }
}

// ---------------- k2a: LN(m) -> mn bf16 [r=(s,n)][64] ----------------
__global__ __launch_bounds__(256) void k2a_ln_m(
    const float* __restrict__ m, const float* __restrict__ mnw,
    const float* __restrict__ mnb, u16* __restrict__ mn) {
  __shared__ float sw[DM], sb[DM];
  const int tid = threadIdx.x;
  if (tid < DM) { sw[tid] = mnw[tid]; sb[tid] = mnb[tid]; }
  __syncthreads();
  const size_t r = (size_t)blockIdx.x * 256 + tid;
  const float4* mp = (const float4*)(m + r * DM);
  float4 arr[16];
  float sum = 0.f, sq = 0.f;
  #pragma unroll
  for (int q = 0; q < 16; ++q) {
    float4 v = mp[q]; arr[q] = v;
    sum += v.x + v.y + v.z + v.w;
    sq  += v.x * v.x + v.y * v.y + v.z * v.z + v.w * v.w;
  }
  const float mu = sum * (1.f / DM);
  const float rs = rsqrtf(sq * (1.f / DM) - mu * mu + 1e-5f);
  uint4* op = (uint4*)(mn + r * DM);
  #pragma unroll
  for (int q = 0; q < 8; ++q) {
    const float4 a = arr[2 * q], b = arr[2 * q + 1];
    const int c0 = q * 8;
    const float y0 = (a.x - mu) * rs * sw[c0 + 0] + sb[c0 + 0];
    const float y1 = (a.y - mu) * rs * sw[c0 + 1] + sb[c0 + 1];
    const float y2 = (a.z - mu) * rs * sw[c0 + 2] + sb[c0 + 2];
    const float y3 = (a.w - mu) * rs * sw[c0 + 3] + sb[c0 + 3];
    const float y4 = (b.x - mu) * rs * sw[c0 + 4] + sb[c0 + 4];
    const float y5 = (b.y - mu) * rs * sw[c0 + 5] + sb[c0 + 5];
    const float y6 = (b.z - mu) * rs * sw[c0 + 6] + sb[c0 + 6];
    const float y7 = (b.w - mu) * rs * sw[c0 + 7] + sb[c0 + 7];
    uint4 u;
    u.x = pack2(y0, y1); u.y = pack2(y2, y3);
    u.z = pack2(y4, y5); u.w = pack2(y6, y7);
    op[q] = u;
  }
}

// ---------------- k2b: v,g = mn @ [Wm|Wg] ----
// v half (normal order): vf[h][jt=j>>5][np][j&31]
// g half (swapped order): lane holds 4 consecutive c -> ushort4 stores into
// g2[h][j][np], np=s*32+k
__global__ __launch_bounds__(256) void k2b_proj(
    const u16* __restrict__ mn, const u16* __restrict__ wmg,
    u16* __restrict__ vf, u16* __restrict__ g2) {
  const int tid = threadIdx.x, lane = tid & 63, wv = tid >> 6;
  const int rbase = (blockIdx.x * 4 + wv) * 16;
  const u16* ap = mn + (size_t)(rbase + (lane & 15)) * DM + ((lane >> 4) & 3) * 8;
  const bf16x8 a0 = ld8(ap);
  const bf16x8 a1 = ld8(ap + 32);
  const u16* bp = wmg + lane * 8;
  const int r0 = rbase + ((lane >> 4) & 3) * 4;
  const int s0 = r0 >> 9;
  const int j0 = r0 & 511;

  {  // v half: c in [0,256), normal operand order (j on reg axis)
    f32x4 acc[16];
    #pragma unroll
    for (int cb = 0; cb < 16; ++cb) acc[cb] = (f32x4){0.f, 0.f, 0.f, 0.f};
    #pragma unroll
    for (int cb = 0; cb < 16; ++cb) {
      acc[cb] = mfma16(a0, ld8(bp + cb * 1024), acc[cb]);
      acc[cb] = mfma16(a1, ld8(bp + cb * 1024 + 512), acc[cb]);
    }
    #pragma unroll
    for (int cb = 0; cb < 16; ++cb) {
      const int c = cb * 16 + (lane & 15);
      const int h = c >> 5, k = c & 31;
      const int np = s0 * HD + k;
      const size_t idx = (((size_t)(h * JT_N + (j0 >> 5)) * NP + np) << 5) + (j0 & 31);
      ushort4 pk;
      pk.x = f2bf(acc[cb][0]); pk.y = f2bf(acc[cb][1]);
      pk.z = f2bf(acc[cb][2]); pk.w = f2bf(acc[cb][3]);
      *(ushort4*)(vf + idx) = pk;
    }
  }
  {  // g half: c in [256,512), SWAPPED operand order (c on reg axis)
    const int r2 = rbase + (lane & 15);
    const int s2 = r2 >> 9, n2 = r2 & 511;
    f32x4 acc[16];
    #pragma unroll
    for (int cb = 0; cb < 16; ++cb) acc[cb] = (f32x4){0.f, 0.f, 0.f, 0.f};
    #pragma unroll
    for (int cb = 0; cb < 16; ++cb) {
      acc[cb] = mfma16(ld8(bp + (cb + 16) * 1024), a0, acc[cb]);
      acc[cb] = mfma16(ld8(bp + (cb + 16) * 1024 + 512), a1, acc[cb]);
    }
    #pragma unroll
    for (int cb = 0; cb < 16; ++cb) {
      const int c0 = cb * 16 + ((lane >> 4) & 3) * 4;  // +rg for rg=0..3
      const int h = c0 >> 5, k0 = c0 & 31;
      ushort4 pk;
      pk.x = f2bf(1.f / (1.f + __expf(-acc[cb][0])));
      pk.y = f2bf(1.f / (1.f + __expf(-acc[cb][1])));
      pk.z = f2bf(1.f / (1.f + __expf(-acc[cb][2])));
      pk.w = f2bf(1.f / (1.f + __expf(-acc[cb][3])));
      *(ushort4*)(g2 + ((size_t)h * N_DIM + n2) * NP + s0 * 0 + s2 * HD + k0) = pk;
    }
  }
}

// ---------------- k3: per-head o = w @ v, counted-vmcnt ring pipeline ----------
// grid dim3(8 h, 4 i-tiles, 64 n'-tiles): XCD k owns head k (idx%8==x).
// Block tile 128x128, BK=32, 4 waves each 64x64 (4x4 16x16 frags).
// 3 LDS slots (prefetch distance 2); s_waitcnt vmcnt(4) per iter — never 0
// in the loop, so 8 staged loads stay in flight across every barrier.
// SWAPPED-operand MFMA: np on reg axis, i on lane axis -> g2 RMW is ushort4.
__global__ __launch_bounds__(256) void k3_pwa(
    const u16* __restrict__ wf, const u16* __restrict__ vf, u16* __restrict__ g2) {
  __shared__ __attribute__((aligned(16))) u16 ring[3][2][128 * BKP];
  const int tid = threadIdx.x, lane = tid & 63, wv = tid >> 6;
  const int wr = wv >> 1, wc = wv & 1;
  const int h = blockIdx.x;
  const int i0 = blockIdx.y * 128;
  const int n0 = blockIdx.z * 128;

  // global K-panel bases (each panel = 128 rows x 32 u16 = 8KB contiguous)
  const char* gA = (const char*)(wf + (((size_t)h * JT_N * N_DIM) + i0) * BKP);
  const char* gB = (const char*)(vf + (((size_t)h * JT_N * NP) + n0) * BKP);

  // per-wave stage: wave wv covers panel bytes [wv*2048, wv*2048+2048)
  const int sbase0 = wv * 2048;
  const int sbase1 = wv * 2048 + 1024;
  const int soff0 = swz(sbase0 + lane * 16);
  const int soff1 = swz(sbase1 + lane * 16);

  f32x4 acc[4][4];
  #pragma unroll
  for (int a = 0; a < 4; ++a)
    #pragma unroll
    for (int b = 0; b < 4; ++b) acc[a][b] = (f32x4){0.f, 0.f, 0.f, 0.f};

  // swizzled LDS read offsets (bytes within panel)
  int offA[4], offB[4];
  #pragma unroll
  for (int f = 0; f < 4; ++f) {
    const int ra = wr * 64 + f * 16 + (lane & 15);
    const int rb = wc * 64 + f * 16 + (lane & 15);
    offA[f] = swz(ra * 64 + ((lane >> 4) & 3) * 16);
    offB[f] = swz(rb * 64 + ((lane >> 4) & 3) * 16);
  }

#define STAGE(jt, slot)                                                  \
  do {                                                                   \
    const char* pA_ = gA + (size_t)(jt) * (N_DIM * BKP * 2);             \
    const char* pB_ = gB + (size_t)(jt) * (NP * BKP * 2);                \
    char* dA_ = (char*)&ring[(slot)][0][0];                              \
    char* dB_ = (char*)&ring[(slot)][1][0];                              \
    gload_lds16(pA_ + soff0, dA_ + sbase0);                              \
    gload_lds16(pA_ + soff1, dA_ + sbase1);                              \
    gload_lds16(pB_ + soff0, dB_ + sbase0);                              \
    gload_lds16(pB_ + soff1, dB_ + sbase1);                              \
  } while (0)

#define COMPUTE(slot)                                                    \
  do {                                                                   \
    const char* cA_ = (const char*)&ring[(slot)][0][0];                  \
    const char* cB_ = (const char*)&ring[(slot)][1][0];                  \
    bf16x8 af_[4], bf_[4];                                               \
    _Pragma("unroll")                                                    \
    for (int f = 0; f < 4; ++f) af_[f] = ld8((const u16*)(cA_ + offA[f]));\
    _Pragma("unroll")                                                    \
    for (int f = 0; f < 4; ++f) bf_[f] = ld8((const u16*)(cB_ + offB[f]));\
    _Pragma("unroll")                                                    \
    for (int fi = 0; fi < 4; ++fi)                                       \
      _Pragma("unroll")                                                  \
      for (int fn = 0; fn < 4; ++fn)                                     \
        acc[fi][fn] = mfma16(bf_[fn], af_[fi], acc[fi][fn]);             \
  } while (0)

  // prologue: tiles 0,1 in flight
  STAGE(0, 0);
  STAGE(1, 1);
  #pragma unroll
  for (int t = 0; t < JT_N - 2; ++t) {
    asm volatile("s_waitcnt vmcnt(4)" ::: "memory");  // tile t landed; t+1 in flight
    BARRIER();
    STAGE(t + 2, (t + 2) % 3);
    COMPUTE(t % 3);
  }
  asm volatile("s_waitcnt vmcnt(4)" ::: "memory");
  BARRIER();
  COMPUTE((JT_N - 2) % 3);
  asm volatile("s_waitcnt vmcnt(0)" ::: "memory");
  BARRIER();
  COMPUTE((JT_N - 1) % 3);
#undef STAGE
#undef COMPUTE

  // epilogue: swapped layout -> lane holds 4 consecutive np for fixed i.
  // gate in place: g2 <- o * g2 (ushort4 RMW, wave-coalesced 32B per row)
  #pragma unroll
  for (int fi = 0; fi < 4; ++fi) {
    const int i = i0 + wr * 64 + fi * 16 + (lane & 15);
    #pragma unroll
    for (int fn = 0; fn < 4; ++fn) {
      const int np0 = n0 + wc * 64 + fn * 16 + ((lane >> 4) & 3) * 4;
      u16* p = g2 + ((size_t)h * N_DIM + i) * NP + np0;
      const ushort4 gv = *(const ushort4*)p;
      ushort4 pk;
      pk.x = f2bf(acc[fi][fn][0] * bf2f(gv.x));
      pk.y = f2bf(acc[fi][fn][1] * bf2f(gv.y));
      pk.z = f2bf(acc[fi][fn][2] * bf2f(gv.z));
      pk.w = f2bf(acc[fi][fn][3] * bf2f(gv.w));
      *(ushort4*)p = pk;
    }
  }
}

// ---------------- k4: out = og @ Wo (f32 out) ----------------
__global__ __launch_bounds__(256) void k4_out(
    const u16* __restrict__ og, const u16* __restrict__ wof,
    float* __restrict__ out) {
  const int tid = threadIdx.x, lane = tid & 63, wv = tid >> 6;
  const int rbase = (blockIdx.x * 4 + wv) * 16;
  const int rl = rbase + (lane & 15);
  const int s = rl >> 9, i = rl & 511;
  const u16* ap = og + (size_t)i * NP + s * HD + ((lane >> 4) & 3) * 8;
  const u16* bp = wof + lane * 8;
  f32x4 acc[4];
  #pragma unroll
  for (int fn = 0; fn < 4; ++fn) acc[fn] = (f32x4){0.f, 0.f, 0.f, 0.f};
  #pragma unroll
  for (int ks = 0; ks < 8; ++ks) {  // ks == head
    const bf16x8 a = ld8(ap + (size_t)ks * 4194304);
    #pragma unroll
    for (int fn = 0; fn < 4; ++fn)
      acc[fn] = mfma16(a, ld8(bp + (fn * 8 + ks) * 512), acc[fn]);
  }
  const int r0 = rbase + ((lane >> 4) & 3) * 4;
  #pragma unroll
  for (int fn = 0; fn < 4; ++fn)
    #pragma unroll
    for (int rg = 0; rg < 4; ++rg)
      out[(size_t)(r0 + rg) * DM + fn * 16 + (lane & 15)] = acc[fn][rg];
}

extern "C" void kernel_launch(void* const* d_in, const int* in_sizes, int n_in,
                              void* d_out, int out_size, void* d_ws, size_t ws_size,
                              hipStream_t stream) {
  const float* m   = (const float*)d_in[0];
  const float* z   = (const float*)d_in[1];
  const float* mnw = (const float*)d_in[2];
  const float* mnb = (const float*)d_in[3];
  const float* znw = (const float*)d_in[4];
  const float* znb = (const float*)d_in[5];
  const float* Wm  = (const float*)d_in[6];
  const float* Wg  = (const float*)d_in[7];
  const float* Wz  = (const float*)d_in[8];
  const float* Wo  = (const float*)d_in[9];
  float* out = (float*)d_out;
  char* ws = (char*)d_ws;

  // ws layout (bytes): wf 4MiB | vf 64MiB | g2 64MiB | mn 16MiB | wmg 64KiB | wof 32KiB
  u16* wbuf = (u16*)(ws);
  u16* vf   = (u16*)(ws + ((size_t)4   << 20));
  u16* g2   = (u16*)(ws + ((size_t)68  << 20));
  u16* mn   = (u16*)(ws + ((size_t)132 << 20));
  u16* wmg  = (u16*)(ws + ((size_t)148 << 20));
  u16* wof  = (u16*)(ws + ((size_t)148 << 20) + 65536);

  k0_prep<<<192, 256, 0, stream>>>(Wm, Wg, Wo, wmg, wof);
  k1_softmax_w<<<512, 256, 0, stream>>>(z, znw, znb, Wz, wbuf);
  k2a_ln_m<<<512, 256, 0, stream>>>(m, mnw, mnb, mn);
  k2b_proj<<<2048, 256, 0, stream>>>(mn, wmg, vf, g2);
  k3_pwa<<<dim3(8, 4, 64), 256, 0, stream>>>(wbuf, vf, g2);
  k4_out<<<2048, 256, 0, stream>>>(g2, wof, out);
}

// Round 4
// 195.227 us; speedup vs baseline: 1.3306x; 1.1903x over previous
//
#include <hip/hip_runtime.h>

// PairWeightedAveraging: m[1,S,N,Dm], z[1,N,N,Dz] -> out[1,S,N,Dm]
// S=256 N=512 Dm=64 Dz=128 H=8 HD=32
// Pipeline (all bf16 MFMA):
//  k0: pre-swizzle [Wm|Wg], Wo, and W'=znw*Wz (split hi/lo bf16) frag tables
//  k1a: bias b[h][i][j] = rs*(z.W'_h - mu*t1[h]) + cst[h] via split-bf16 MFMA
//  k1b: row softmax over j -> wf[h][jt][i][32] bf16 (K-panel layout)
//  k2a: LN(m) -> mn bf16
//  k2b: v,g = mn @ [Wm|Wg]; v -> vf[h][jt][np][32]; g=sigmoid -> g2[h][j][np]
//  k3: per-head GEMM o = w @ v, counted-vmcnt 3-slot ring pipeline,
//      swapped-operand MFMA -> vectorized g2 gate-RMW in place
//  k4: out = og @ Wo (og layout is A-fragment-native)

#define S_DIM 256
#define N_DIM 512
#define DM 64
#define DZ 128
#define NH 8
#define HD 32
#define HK 256
#define NP 8192  // S_DIM*HD
#define BKP 32   // k3 K-panel depth
#define JT_N 16  // 512 / BKP

typedef unsigned int   u32;
typedef unsigned short u16;
typedef __bf16 bf16x8 __attribute__((ext_vector_type(8)));
typedef float  f32x4  __attribute__((ext_vector_type(4)));
typedef u32    u32x4  __attribute__((ext_vector_type(4)));

__device__ __forceinline__ u16 f2bf(float f) {
  u32 u = __builtin_bit_cast(u32, f);
  return (u16)((u + 0x7FFFu + ((u >> 16) & 1u)) >> 16);  // RNE
}
__device__ __forceinline__ float bf2f(u16 h) {
  u32 u = ((u32)h) << 16;
  return __builtin_bit_cast(float, u);
}
__device__ __forceinline__ u32 pack2(float a, float b) {
  return (u32)f2bf(a) | ((u32)f2bf(b) << 16);
}
__device__ __forceinline__ bf16x8 ld8(const u16* p) {
  return __builtin_bit_cast(bf16x8, *(const u32x4*)p);
}
__device__ __forceinline__ f32x4 mfma16(bf16x8 a, bf16x8 b, f32x4 c) {
  return __builtin_amdgcn_mfma_f32_16x16x32_bf16(a, b, c, 0, 0, 0);
}
__device__ __forceinline__ void gload_lds16(const void* gsrc, void* ldst) {
  __builtin_amdgcn_global_load_lds(
      (const __attribute__((address_space(1))) void*)gsrc,
      (__attribute__((address_space(3))) void*)ldst, 16, 0, 0);
}
// panel byte-offset swizzle (involution; permutes 16B chunks within 8 rows of 64B)
__device__ __forceinline__ int swz(int lin) { return lin ^ (((lin >> 7) & 3) << 4); }

#define BARRIER() do { asm volatile("" ::: "memory"); \
                       __builtin_amdgcn_s_barrier();  \
                       asm volatile("" ::: "memory"); } while (0)

// ---------------- k0: weight fragment tables ----------------
// wmg: [cb(32)][ks(2)][lane(64)][t(8)]  c=cb*16+(lane&15), k=ks*32+(lane>>4)*8+t
// wof: [cb(4)][ks(8)][lane(64)][t(8)]   c=cb*16+(lane&15), hk=ks*32+(lane>>4)*8+t
// wzf: [ks(4)][p(2)][lane(64)][t(8)]    h=lane&15 (<8), k=ks*32+(lane>>4)*8+t
//       p=0: hi(W'[k][h]), p=1: lo;  W' = znw[k]*Wz[k][h]
// t1c: [0..7]=t1[h]=sum_c W'[c][h]; [8..15]=cst[h]=sum_c znb[c]*Wz[c][h]
__global__ __launch_bounds__(256) void k0_prep(
    const float* __restrict__ Wm, const float* __restrict__ Wg,
    const float* __restrict__ Wo, const float* __restrict__ znw,
    const float* __restrict__ znb, const float* __restrict__ Wz,
    u16* __restrict__ wmg, u16* __restrict__ wof,
    u16* __restrict__ wzf, float* __restrict__ t1c) {
  const int idx = blockIdx.x * 256 + threadIdx.x;
  if (idx < 32768) {
    const int t = idx & 7, lane = (idx >> 3) & 63, ks = (idx >> 9) & 1, cb = idx >> 10;
    const int c = cb * 16 + (lane & 15);
    const int k = ks * 32 + ((lane >> 4) & 3) * 8 + t;
    const float v = (c < HK) ? Wm[k * HK + c] : Wg[k * HK + (c - HK)];
    wmg[idx] = f2bf(v);
  } else if (idx < 32768 + 16384) {
    const int j = idx - 32768;
    const int t = j & 7, lane = (j >> 3) & 63, ks = (j >> 9) & 7, cb = j >> 12;
    const int c = cb * 16 + (lane & 15);
    const int hk = ks * 32 + ((lane >> 4) & 3) * 8 + t;
    wof[j] = f2bf(Wo[hk * DM + c]);
  } else if (idx < 49152 + 4096) {
    const int q = idx - 49152;
    const int t = q & 7, lane = (q >> 3) & 63, p = (q >> 9) & 1, ks = q >> 10;
    const int h = lane & 15;
    const int k = ks * 32 + ((lane >> 4) & 3) * 8 + t;
    u16 val = 0;
    if (h < NH) {
      const float wp = znw[k] * Wz[k * NH + h];
      const u16 hi = f2bf(wp);
      val = (p == 0) ? hi : f2bf(wp - bf2f(hi));
    }
    wzf[q] = val;
  } else if (idx < 49152 + 4096 + 16) {
    const int q = idx - 49152 - 4096;  // 0..15
    const int h = q & 7;
    float s = 0.f;
    for (int c = 0; c < DZ; ++c)
      s += ((q < 8) ? znw[c] : znb[c]) * Wz[c * NH + h];
    t1c[q] = s;
  }
}

// ---------------- k1a: bias via split-bf16 MFMA ----------------
// grid dim3(8 jb, 512 i); wave handles 16 j rows; writes bws[h][i][j] f32
__global__ __launch_bounds__(256) void k1a_bias(
    const float* __restrict__ z, const u16* __restrict__ wzf,
    const float* __restrict__ t1c, float* __restrict__ bws) {
  __shared__ float sB[NH][72];
  const int tid = threadIdx.x, lane = tid & 63, wv = tid >> 6;
  const int jb = blockIdx.x, i = blockIdx.y;
  const int jrow = jb * 64 + wv * 16 + (lane & 15);
  const float* zp = z + ((size_t)i * N_DIM + jrow) * DZ + ((lane >> 4) & 3) * 8;
  f32x4 acc = (f32x4){0.f, 0.f, 0.f, 0.f};
  float sum = 0.f, sq = 0.f;
  #pragma unroll
  for (int ks = 0; ks < 4; ++ks) {
    const float4 v0 = *(const float4*)(zp + ks * 32);
    const float4 v1 = *(const float4*)(zp + ks * 32 + 4);
    const float xs[8] = {v0.x, v0.y, v0.z, v0.w, v1.x, v1.y, v1.z, v1.w};
    bf16x8 zh, zl;
    #pragma unroll
    for (int t = 0; t < 8; ++t) {
      sum += xs[t]; sq += xs[t] * xs[t];
      const u16 h16 = f2bf(xs[t]);
      ((u16*)&zh)[t] = h16;
      ((u16*)&zl)[t] = f2bf(xs[t] - bf2f(h16));
    }
    const bf16x8 wh = ld8(wzf + (ks * 2 + 0) * 512 + lane * 8);
    const bf16x8 wl = ld8(wzf + (ks * 2 + 1) * 512 + lane * 8);
    acc = mfma16(zh, wh, acc);
    acc = mfma16(zl, wh, acc);
    acc = mfma16(zh, wl, acc);
  }
  sum += __shfl_xor(sum, 16, 64); sum += __shfl_xor(sum, 32, 64);
  sq  += __shfl_xor(sq, 16, 64);  sq  += __shfl_xor(sq, 32, 64);
  const float mu = sum * (1.f / DZ);
  const float rs = rsqrtf(sq * (1.f / DZ) - mu * mu + 1e-5f);
  const int h = lane & 15;
  const float t1 = t1c[h & 7], cst = t1c[8 + (h & 7)];
  #pragma unroll
  for (int rg = 0; rg < 4; ++rg) {
    const int r = ((lane >> 4) & 3) * 4 + rg;
    const float mur = __shfl(mu, r, 64);
    const float rsr = __shfl(rs, r, 64);
    const float bv = rsr * (acc[rg] - mur * t1) + cst;
    if (h < NH) sB[h][wv * 16 + r] = bv;
  }
  __syncthreads();
  #pragma unroll
  for (int q = 0; q < 2; ++q) {
    const int idx = tid + q * 256;
    const int hh = idx >> 6, jl = idx & 63;
    bws[((size_t)hh * N_DIM + i) * N_DIM + jb * 64 + jl] = sB[hh][jl];
  }
}

// ---------------- k1b: row softmax -> wf bf16 K-panel layout ----------------
// wf layout: [h][jt=j>>5][i][j&31]; one wave per row (h,i)
__global__ __launch_bounds__(256) void k1b_softmax(
    const float* __restrict__ bws, u16* __restrict__ wout) {
  const int tid = threadIdx.x, lane = tid & 63, wv = tid >> 6;
  const int row = blockIdx.x * 4 + wv;  // row = h*512 + i
  const int h = row >> 9, i = row & 511;
  const float* bp = bws + (size_t)row * N_DIM + lane * 8;
  const float4 v0 = *(const float4*)bp;
  const float4 v1 = *(const float4*)(bp + 4);
  float xs[8] = {v0.x, v0.y, v0.z, v0.w, v1.x, v1.y, v1.z, v1.w};
  float mx = xs[0];
  #pragma unroll
  for (int t = 1; t < 8; ++t) mx = fmaxf(mx, xs[t]);
  #pragma unroll
  for (int off = 32; off; off >>= 1) mx = fmaxf(mx, __shfl_xor(mx, off, 64));
  float sm = 0.f;
  #pragma unroll
  for (int t = 0; t < 8; ++t) { xs[t] = __expf(xs[t] - mx); sm += xs[t]; }
  #pragma unroll
  for (int off = 32; off; off >>= 1) sm += __shfl_xor(sm, off, 64);
  const float inv = 1.f / sm;
  u32x4 pk;
  pk[0] = pack2(xs[0] * inv, xs[1] * inv);
  pk[1] = pack2(xs[2] * inv, xs[3] * inv);
  pk[2] = pack2(xs[4] * inv, xs[5] * inv);
  pk[3] = pack2(xs[6] * inv, xs[7] * inv);
  *(u32x4*)(wout + (((size_t)(h * JT_N + (lane >> 2)) * N_DIM + i) << 5)
            + (lane & 3) * 8) = pk;
}

// ---------------- k2a: LN(m) -> mn bf16 [r=(s,n)][64] ----------------
__global__ __launch_bounds__(256) void k2a_ln_m(
    const float* __restrict__ m, const float* __restrict__ mnw,
    const float* __restrict__ mnb, u16* __restrict__ mn) {
  __shared__ float sw[DM], sb[DM];
  const int tid = threadIdx.x;
  if (tid < DM) { sw[tid] = mnw[tid]; sb[tid] = mnb[tid]; }
  __syncthreads();
  const size_t r = (size_t)blockIdx.x * 256 + tid;
  const float4* mp = (const float4*)(m + r * DM);
  float4 arr[16];
  float sum = 0.f, sq = 0.f;
  #pragma unroll
  for (int q = 0; q < 16; ++q) {
    float4 v = mp[q]; arr[q] = v;
    sum += v.x + v.y + v.z + v.w;
    sq  += v.x * v.x + v.y * v.y + v.z * v.z + v.w * v.w;
  }
  const float mu = sum * (1.f / DM);
  const float rs = rsqrtf(sq * (1.f / DM) - mu * mu + 1e-5f);
  uint4* op = (uint4*)(mn + r * DM);
  #pragma unroll
  for (int q = 0; q < 8; ++q) {
    const float4 a = arr[2 * q], b = arr[2 * q + 1];
    const int c0 = q * 8;
    const float y0 = (a.x - mu) * rs * sw[c0 + 0] + sb[c0 + 0];
    const float y1 = (a.y - mu) * rs * sw[c0 + 1] + sb[c0 + 1];
    const float y2 = (a.z - mu) * rs * sw[c0 + 2] + sb[c0 + 2];
    const float y3 = (a.w - mu) * rs * sw[c0 + 3] + sb[c0 + 3];
    const float y4 = (b.x - mu) * rs * sw[c0 + 4] + sb[c0 + 4];
    const float y5 = (b.y - mu) * rs * sw[c0 + 5] + sb[c0 + 5];
    const float y6 = (b.z - mu) * rs * sw[c0 + 6] + sb[c0 + 6];
    const float y7 = (b.w - mu) * rs * sw[c0 + 7] + sb[c0 + 7];
    uint4 u;
    u.x = pack2(y0, y1); u.y = pack2(y2, y3);
    u.z = pack2(y4, y5); u.w = pack2(y6, y7);
    op[q] = u;
  }
}

// ---------------- k2b: v,g = mn @ [Wm|Wg] ----
// v half (normal order): vf[h][jt=j>>5][np][j&31]
// g half (swapped order): lane holds 4 consecutive c -> ushort4 stores into
// g2[h][j][np], np=s*32+k
__global__ __launch_bounds__(256) void k2b_proj(
    const u16* __restrict__ mn, const u16* __restrict__ wmg,
    u16* __restrict__ vf, u16* __restrict__ g2) {
  const int tid = threadIdx.x, lane = tid & 63, wv = tid >> 6;
  const int rbase = (blockIdx.x * 4 + wv) * 16;
  const u16* ap = mn + (size_t)(rbase + (lane & 15)) * DM + ((lane >> 4) & 3) * 8;
  const bf16x8 a0 = ld8(ap);
  const bf16x8 a1 = ld8(ap + 32);
  const u16* bp = wmg + lane * 8;
  const int r0 = rbase + ((lane >> 4) & 3) * 4;
  const int s0 = r0 >> 9;
  const int j0 = r0 & 511;

  {  // v half: c in [0,256), normal operand order (j on reg axis)
    f32x4 acc[16];
    #pragma unroll
    for (int cb = 0; cb < 16; ++cb) acc[cb] = (f32x4){0.f, 0.f, 0.f, 0.f};
    #pragma unroll
    for (int cb = 0; cb < 16; ++cb) {
      acc[cb] = mfma16(a0, ld8(bp + cb * 1024), acc[cb]);
      acc[cb] = mfma16(a1, ld8(bp + cb * 1024 + 512), acc[cb]);
    }
    #pragma unroll
    for (int cb = 0; cb < 16; ++cb) {
      const int c = cb * 16 + (lane & 15);
      const int h = c >> 5, k = c & 31;
      const int np = s0 * HD + k;
      const size_t idx = (((size_t)(h * JT_N + (j0 >> 5)) * NP + np) << 5) + (j0 & 31);
      ushort4 pk;
      pk.x = f2bf(acc[cb][0]); pk.y = f2bf(acc[cb][1]);
      pk.z = f2bf(acc[cb][2]); pk.w = f2bf(acc[cb][3]);
      *(ushort4*)(vf + idx) = pk;
    }
  }
  {  // g half: c in [256,512), SWAPPED operand order (c on reg axis)
    const int r2 = rbase + (lane & 15);
    const int s2 = r2 >> 9, n2 = r2 & 511;
    f32x4 acc[16];
    #pragma unroll
    for (int cb = 0; cb < 16; ++cb) acc[cb] = (f32x4){0.f, 0.f, 0.f, 0.f};
    #pragma unroll
    for (int cb = 0; cb < 16; ++cb) {
      acc[cb] = mfma16(ld8(bp + (cb + 16) * 1024), a0, acc[cb]);
      acc[cb] = mfma16(ld8(bp + (cb + 16) * 1024 + 512), a1, acc[cb]);
    }
    #pragma unroll
    for (int cb = 0; cb < 16; ++cb) {
      const int c0 = cb * 16 + ((lane >> 4) & 3) * 4;  // +rg for rg=0..3
      const int h = c0 >> 5, k0 = c0 & 31;
      ushort4 pk;
      pk.x = f2bf(1.f / (1.f + __expf(-acc[cb][0])));
      pk.y = f2bf(1.f / (1.f + __expf(-acc[cb][1])));
      pk.z = f2bf(1.f / (1.f + __expf(-acc[cb][2])));
      pk.w = f2bf(1.f / (1.f + __expf(-acc[cb][3])));
      *(ushort4*)(g2 + ((size_t)h * N_DIM + n2) * NP + s2 * HD + k0) = pk;
    }
  }
}

// ---------------- k3: per-head o = w @ v, counted-vmcnt ring pipeline ----------
// grid dim3(8 h, 4 i-tiles, 64 n'-tiles): XCD k owns head k (idx%8==x).
// Block tile 128x128, BK=32, 4 waves each 64x64 (4x4 16x16 frags).
// 3 LDS slots (prefetch distance 2); s_waitcnt vmcnt(4) per iter — never 0
// in the loop, so 8 staged loads stay in flight across every barrier.
// SWAPPED-operand MFMA: np on reg axis, i on lane axis -> g2 RMW is ushort4.
__global__ __launch_bounds__(256) void k3_pwa(
    const u16* __restrict__ wf, const u16* __restrict__ vf, u16* __restrict__ g2) {
  __shared__ __attribute__((aligned(16))) u16 ring[3][2][128 * BKP];
  const int tid = threadIdx.x, lane = tid & 63, wv = tid >> 6;
  const int wr = wv >> 1, wc = wv & 1;
  const int h = blockIdx.x;
  const int i0 = blockIdx.y * 128;
  const int n0 = blockIdx.z * 128;

  // global K-panel bases (each panel = 128 rows x 32 u16 = 8KB contiguous)
  const char* gA = (const char*)(wf + (((size_t)h * JT_N * N_DIM) + i0) * BKP);
  const char* gB = (const char*)(vf + (((size_t)h * JT_N * NP) + n0) * BKP);

  // per-wave stage: wave wv covers panel bytes [wv*2048, wv*2048+2048)
  const int sbase0 = wv * 2048;
  const int sbase1 = wv * 2048 + 1024;
  const int soff0 = swz(sbase0 + lane * 16);
  const int soff1 = swz(sbase1 + lane * 16);

  f32x4 acc[4][4];
  #pragma unroll
  for (int a = 0; a < 4; ++a)
    #pragma unroll
    for (int b = 0; b < 4; ++b) acc[a][b] = (f32x4){0.f, 0.f, 0.f, 0.f};

  // swizzled LDS read offsets (bytes within panel)
  int offA[4], offB[4];
  #pragma unroll
  for (int f = 0; f < 4; ++f) {
    const int ra = wr * 64 + f * 16 + (lane & 15);
    const int rb = wc * 64 + f * 16 + (lane & 15);
    offA[f] = swz(ra * 64 + ((lane >> 4) & 3) * 16);
    offB[f] = swz(rb * 64 + ((lane >> 4) & 3) * 16);
  }

#define STAGE(jt, slot)                                                  \
  do {                                                                   \
    const char* pA_ = gA + (size_t)(jt) * (N_DIM * BKP * 2);             \
    const char* pB_ = gB + (size_t)(jt) * (NP * BKP * 2);                \
    char* dA_ = (char*)&ring[(slot)][0][0];                              \
    char* dB_ = (char*)&ring[(slot)][1][0];                              \
    gload_lds16(pA_ + soff0, dA_ + sbase0);                              \
    gload_lds16(pA_ + soff1, dA_ + sbase1);                              \
    gload_lds16(pB_ + soff0, dB_ + sbase0);                              \
    gload_lds16(pB_ + soff1, dB_ + sbase1);                              \
  } while (0)

#define COMPUTE(slot)                                                    \
  do {                                                                   \
    const char* cA_ = (const char*)&ring[(slot)][0][0];                  \
    const char* cB_ = (const char*)&ring[(slot)][1][0];                  \
    bf16x8 af_[4], bf_[4];                                               \
    _Pragma("unroll")                                                    \
    for (int f = 0; f < 4; ++f) af_[f] = ld8((const u16*)(cA_ + offA[f]));\
    _Pragma("unroll")                                                    \
    for (int f = 0; f < 4; ++f) bf_[f] = ld8((const u16*)(cB_ + offB[f]));\
    _Pragma("unroll")                                                    \
    for (int fi = 0; fi < 4; ++fi)                                       \
      _Pragma("unroll")                                                  \
      for (int fn = 0; fn < 4; ++fn)                                     \
        acc[fi][fn] = mfma16(bf_[fn], af_[fi], acc[fi][fn]);             \
  } while (0)

  // prologue: tiles 0,1 in flight
  STAGE(0, 0);
  STAGE(1, 1);
  #pragma unroll
  for (int t = 0; t < JT_N - 2; ++t) {
    asm volatile("s_waitcnt vmcnt(4)" ::: "memory");  // tile t landed; t+1 in flight
    BARRIER();
    STAGE(t + 2, (t + 2) % 3);
    COMPUTE(t % 3);
  }
  asm volatile("s_waitcnt vmcnt(4)" ::: "memory");
  BARRIER();
  COMPUTE((JT_N - 2) % 3);
  asm volatile("s_waitcnt vmcnt(0)" ::: "memory");
  BARRIER();
  COMPUTE((JT_N - 1) % 3);
#undef STAGE
#undef COMPUTE

  // epilogue: swapped layout -> lane holds 4 consecutive np for fixed i.
  // gate in place: g2 <- o * g2 (ushort4 RMW, wave-coalesced 32B per row)
  #pragma unroll
  for (int fi = 0; fi < 4; ++fi) {
    const int i = i0 + wr * 64 + fi * 16 + (lane & 15);
    #pragma unroll
    for (int fn = 0; fn < 4; ++fn) {
      const int np0 = n0 + wc * 64 + fn * 16 + ((lane >> 4) & 3) * 4;
      u16* p = g2 + ((size_t)h * N_DIM + i) * NP + np0;
      const ushort4 gv = *(const ushort4*)p;
      ushort4 pk;
      pk.x = f2bf(acc[fi][fn][0] * bf2f(gv.x));
      pk.y = f2bf(acc[fi][fn][1] * bf2f(gv.y));
      pk.z = f2bf(acc[fi][fn][2] * bf2f(gv.z));
      pk.w = f2bf(acc[fi][fn][3] * bf2f(gv.w));
      *(ushort4*)p = pk;
    }
  }
}

// ---------------- k4: out = og @ Wo (f32 out) ----------------
__global__ __launch_bounds__(256) void k4_out(
    const u16* __restrict__ og, const u16* __restrict__ wof,
    float* __restrict__ out) {
  const int tid = threadIdx.x, lane = tid & 63, wv = tid >> 6;
  const int rbase = (blockIdx.x * 4 + wv) * 16;
  const int rl = rbase + (lane & 15);
  const int s = rl >> 9, i = rl & 511;
  const u16* ap = og + (size_t)i * NP + s * HD + ((lane >> 4) & 3) * 8;
  const u16* bp = wof + lane * 8;
  f32x4 acc[4];
  #pragma unroll
  for (int fn = 0; fn < 4; ++fn) acc[fn] = (f32x4){0.f, 0.f, 0.f, 0.f};
  #pragma unroll
  for (int ks = 0; ks < 8; ++ks) {  // ks == head
    const bf16x8 a = ld8(ap + (size_t)ks * 4194304);
    #pragma unroll
    for (int fn = 0; fn < 4; ++fn)
      acc[fn] = mfma16(a, ld8(bp + (fn * 8 + ks) * 512), acc[fn]);
  }
  const int r0 = rbase + ((lane >> 4) & 3) * 4;
  #pragma unroll
  for (int fn = 0; fn < 4; ++fn)
    #pragma unroll
    for (int rg = 0; rg < 4; ++rg)
      out[(size_t)(r0 + rg) * DM + fn * 16 + (lane & 15)] = acc[fn][rg];
}

extern "C" void kernel_launch(void* const* d_in, const int* in_sizes, int n_in,
                              void* d_out, int out_size, void* d_ws, size_t ws_size,
                              hipStream_t stream) {
  const float* m   = (const float*)d_in[0];
  const float* z   = (const float*)d_in[1];
  const float* mnw = (const float*)d_in[2];
  const float* mnb = (const float*)d_in[3];
  const float* znw = (const float*)d_in[4];
  const float* znb = (const float*)d_in[5];
  const float* Wm  = (const float*)d_in[6];
  const float* Wg  = (const float*)d_in[7];
  const float* Wz  = (const float*)d_in[8];
  const float* Wo  = (const float*)d_in[9];
  float* out = (float*)d_out;
  char* ws = (char*)d_ws;

  // ws layout (bytes): wf 4MiB | vf 64MiB | g2 64MiB | mn 16MiB | wmg 64KiB |
  //                    wof 32KiB | wzf 8KiB | t1c 64B
  // bws (8MiB f32) overlaps mn: k1a writes / k1b reads it BEFORE k2a writes mn.
  u16*   wbuf = (u16*)(ws);
  u16*   vf   = (u16*)(ws + ((size_t)4   << 20));
  u16*   g2   = (u16*)(ws + ((size_t)68  << 20));
  u16*   mn   = (u16*)(ws + ((size_t)132 << 20));
  float* bws  = (float*)(ws + ((size_t)132 << 20));
  u16*   wmg  = (u16*)(ws + ((size_t)148 << 20));
  u16*   wof  = (u16*)(ws + ((size_t)148 << 20) + 65536);
  u16*   wzf  = (u16*)(ws + ((size_t)148 << 20) + 98304);
  float* t1c  = (float*)(ws + ((size_t)148 << 20) + 106496);

  k0_prep<<<209, 256, 0, stream>>>(Wm, Wg, Wo, znw, znb, Wz, wmg, wof, wzf, t1c);
  k1a_bias<<<dim3(8, 512), 256, 0, stream>>>(z, wzf, t1c, bws);
  k1b_softmax<<<1024, 256, 0, stream>>>(bws, wbuf);
  k2a_ln_m<<<512, 256, 0, stream>>>(m, mnw, mnb, mn);
  k2b_proj<<<2048, 256, 0, stream>>>(mn, wmg, vf, g2);
  k3_pwa<<<dim3(8, 4, 64), 256, 0, stream>>>(wbuf, vf, g2);
  k4_out<<<2048, 256, 0, stream>>>(g2, wof, out);
}

// Round 5
// 167.569 us; speedup vs baseline: 1.5502x; 1.1651x over previous
//
#include <hip/hip_runtime.h>

// PairWeightedAveraging: m[1,S,N,Dm], z[1,N,N,Dz] -> out[1,S,N,Dm]
// S=256 N=512 Dm=64 Dz=128 H=8 HD=32
// Pipeline (all bf16 MFMA):
//  k0: pre-swizzle [Wm|Wg], Wo, and W'=znw*Wz (split hi/lo bf16) frag tables
//  k1a: bias b[h][i][j] = rs*(z.W'_h - mu*t1[h]) + cst[h] via split-bf16 MFMA
//  k1b: row softmax over j -> wf[h][jt][i][32] bf16 (K-panel layout)
//  k2a: LN(m) -> mn bf16
//  k2b: v = mn @ Wm -> vf[h][jt][np][32]   (g no longer materialized)
//  k3: per-head GEMM o = w @ v, counted-vmcnt 3-slot ring pipeline,
//      pure bf16 store of o into ob (A-frag-native for k4)
//  k4: g = sigmoid(mn @ Wg) recomputed via MFMA (+LDS layout bounce),
//      gate o in-register, project through Wo -> out (f32)

#define S_DIM 256
#define N_DIM 512
#define DM 64
#define DZ 128
#define NH 8
#define HD 32
#define HK 256
#define NP 8192  // S_DIM*HD
#define BKP 32   // k3 K-panel depth
#define JT_N 16  // 512 / BKP

typedef unsigned int   u32;
typedef unsigned short u16;
typedef __bf16 bf16x8 __attribute__((ext_vector_type(8)));
typedef float  f32x4  __attribute__((ext_vector_type(4)));
typedef u32    u32x4  __attribute__((ext_vector_type(4)));

__device__ __forceinline__ u16 f2bf(float f) {
  u32 u = __builtin_bit_cast(u32, f);
  return (u16)((u + 0x7FFFu + ((u >> 16) & 1u)) >> 16);  // RNE
}
__device__ __forceinline__ float bf2f(u16 h) {
  u32 u = ((u32)h) << 16;
  return __builtin_bit_cast(float, u);
}
__device__ __forceinline__ u32 pack2(float a, float b) {
  return (u32)f2bf(a) | ((u32)f2bf(b) << 16);
}
__device__ __forceinline__ bf16x8 ld8(const u16* p) {
  return __builtin_bit_cast(bf16x8, *(const u32x4*)p);
}
__device__ __forceinline__ f32x4 mfma16(bf16x8 a, bf16x8 b, f32x4 c) {
  return __builtin_amdgcn_mfma_f32_16x16x32_bf16(a, b, c, 0, 0, 0);
}
__device__ __forceinline__ void gload_lds16(const void* gsrc, void* ldst) {
  __builtin_amdgcn_global_load_lds(
      (const __attribute__((address_space(1))) void*)gsrc,
      (__attribute__((address_space(3))) void*)ldst, 16, 0, 0);
}
// panel byte-offset swizzle (involution; permutes 16B chunks within 8 rows of 64B)
__device__ __forceinline__ int swz(int lin) { return lin ^ (((lin >> 7) & 3) << 4); }

#define BARRIER() do { asm volatile("" ::: "memory"); \
                       __builtin_amdgcn_s_barrier();  \
                       asm volatile("" ::: "memory"); } while (0)

// ---------------- k0: weight fragment tables ----------------
// wmg: [cb(32)][ks(2)][lane(64)][t(8)]  c=cb*16+(lane&15), k=ks*32+(lane>>4)*8+t
// wof: [cb(4)][ks(8)][lane(64)][t(8)]   c=cb*16+(lane&15), hk=ks*32+(lane>>4)*8+t
// wzf: [ks(4)][p(2)][lane(64)][t(8)]    h=lane&15 (<8), k=ks*32+(lane>>4)*8+t
//       p=0: hi(W'[k][h]), p=1: lo;  W' = znw[k]*Wz[k][h]
// t1c: [0..7]=t1[h]=sum_c W'[c][h]; [8..15]=cst[h]=sum_c znb[c]*Wz[c][h]
__global__ __launch_bounds__(256) void k0_prep(
    const float* __restrict__ Wm, const float* __restrict__ Wg,
    const float* __restrict__ Wo, const float* __restrict__ znw,
    const float* __restrict__ znb, const float* __restrict__ Wz,
    u16* __restrict__ wmg, u16* __restrict__ wof,
    u16* __restrict__ wzf, float* __restrict__ t1c) {
  const int idx = blockIdx.x * 256 + threadIdx.x;
  if (idx < 32768) {
    const int t = idx & 7, lane = (idx >> 3) & 63, ks = (idx >> 9) & 1, cb = idx >> 10;
    const int c = cb * 16 + (lane & 15);
    const int k = ks * 32 + ((lane >> 4) & 3) * 8 + t;
    const float v = (c < HK) ? Wm[k * HK + c] : Wg[k * HK + (c - HK)];
    wmg[idx] = f2bf(v);
  } else if (idx < 32768 + 16384) {
    const int j = idx - 32768;
    const int t = j & 7, lane = (j >> 3) & 63, ks = (j >> 9) & 7, cb = j >> 12;
    const int c = cb * 16 + (lane & 15);
    const int hk = ks * 32 + ((lane >> 4) & 3) * 8 + t;
    wof[j] = f2bf(Wo[hk * DM + c]);
  } else if (idx < 49152 + 4096) {
    const int q = idx - 49152;
    const int t = q & 7, lane = (q >> 3) & 63, p = (q >> 9) & 1, ks = q >> 10;
    const int h = lane & 15;
    const int k = ks * 32 + ((lane >> 4) & 3) * 8 + t;
    u16 val = 0;
    if (h < NH) {
      const float wp = znw[k] * Wz[k * NH + h];
      const u16 hi = f2bf(wp);
      val = (p == 0) ? hi : f2bf(wp - bf2f(hi));
    }
    wzf[q] = val;
  } else if (idx < 49152 + 4096 + 16) {
    const int q = idx - 49152 - 4096;  // 0..15
    const int h = q & 7;
    float s = 0.f;
    for (int c = 0; c < DZ; ++c)
      s += ((q < 8) ? znw[c] : znb[c]) * Wz[c * NH + h];
    t1c[q] = s;
  }
}

// ---------------- k1a: bias via split-bf16 MFMA ----------------
// grid dim3(8 jb, 512 i); wave handles 16 j rows; writes bws[h][i][j] f32
__global__ __launch_bounds__(256) void k1a_bias(
    const float* __restrict__ z, const u16* __restrict__ wzf,
    const float* __restrict__ t1c, float* __restrict__ bws) {
  __shared__ float sB[NH][72];
  const int tid = threadIdx.x, lane = tid & 63, wv = tid >> 6;
  const int jb = blockIdx.x, i = blockIdx.y;
  const int jrow = jb * 64 + wv * 16 + (lane & 15);
  const float* zp = z + ((size_t)i * N_DIM + jrow) * DZ + ((lane >> 4) & 3) * 8;
  f32x4 acc = (f32x4){0.f, 0.f, 0.f, 0.f};
  float sum = 0.f, sq = 0.f;
  #pragma unroll
  for (int ks = 0; ks < 4; ++ks) {
    const float4 v0 = *(const float4*)(zp + ks * 32);
    const float4 v1 = *(const float4*)(zp + ks * 32 + 4);
    const float xs[8] = {v0.x, v0.y, v0.z, v0.w, v1.x, v1.y, v1.z, v1.w};
    bf16x8 zh, zl;
    #pragma unroll
    for (int t = 0; t < 8; ++t) {
      sum += xs[t]; sq += xs[t] * xs[t];
      const u16 h16 = f2bf(xs[t]);
      ((u16*)&zh)[t] = h16;
      ((u16*)&zl)[t] = f2bf(xs[t] - bf2f(h16));
    }
    const bf16x8 wh = ld8(wzf + (ks * 2 + 0) * 512 + lane * 8);
    const bf16x8 wl = ld8(wzf + (ks * 2 + 1) * 512 + lane * 8);
    acc = mfma16(zh, wh, acc);
    acc = mfma16(zl, wh, acc);
    acc = mfma16(zh, wl, acc);
  }
  sum += __shfl_xor(sum, 16, 64); sum += __shfl_xor(sum, 32, 64);
  sq  += __shfl_xor(sq, 16, 64);  sq  += __shfl_xor(sq, 32, 64);
  const float mu = sum * (1.f / DZ);
  const float rs = rsqrtf(sq * (1.f / DZ) - mu * mu + 1e-5f);
  const int h = lane & 15;
  const float t1 = t1c[h & 7], cst = t1c[8 + (h & 7)];
  #pragma unroll
  for (int rg = 0; rg < 4; ++rg) {
    const int r = ((lane >> 4) & 3) * 4 + rg;
    const float mur = __shfl(mu, r, 64);
    const float rsr = __shfl(rs, r, 64);
    const float bv = rsr * (acc[rg] - mur * t1) + cst;
    if (h < NH) sB[h][wv * 16 + r] = bv;
  }
  __syncthreads();
  #pragma unroll
  for (int q = 0; q < 2; ++q) {
    const int idx = tid + q * 256;
    const int hh = idx >> 6, jl = idx & 63;
    bws[((size_t)hh * N_DIM + i) * N_DIM + jb * 64 + jl] = sB[hh][jl];
  }
}

// ---------------- k1b: row softmax -> wf bf16 K-panel layout ----------------
// wf layout: [h][jt=j>>5][i][j&31]; one wave per row (h,i)
__global__ __launch_bounds__(256) void k1b_softmax(
    const float* __restrict__ bws, u16* __restrict__ wout) {
  const int tid = threadIdx.x, lane = tid & 63, wv = tid >> 6;
  const int row = blockIdx.x * 4 + wv;  // row = h*512 + i
  const int h = row >> 9, i = row & 511;
  const float* bp = bws + (size_t)row * N_DIM + lane * 8;
  const float4 v0 = *(const float4*)bp;
  const float4 v1 = *(const float4*)(bp + 4);
  float xs[8] = {v0.x, v0.y, v0.z, v0.w, v1.x, v1.y, v1.z, v1.w};
  float mx = xs[0];
  #pragma unroll
  for (int t = 1; t < 8; ++t) mx = fmaxf(mx, xs[t]);
  #pragma unroll
  for (int off = 32; off; off >>= 1) mx = fmaxf(mx, __shfl_xor(mx, off, 64));
  float sm = 0.f;
  #pragma unroll
  for (int t = 0; t < 8; ++t) { xs[t] = __expf(xs[t] - mx); sm += xs[t]; }
  #pragma unroll
  for (int off = 32; off; off >>= 1) sm += __shfl_xor(sm, off, 64);
  const float inv = 1.f / sm;
  u32x4 pk;
  pk[0] = pack2(xs[0] * inv, xs[1] * inv);
  pk[1] = pack2(xs[2] * inv, xs[3] * inv);
  pk[2] = pack2(xs[4] * inv, xs[5] * inv);
  pk[3] = pack2(xs[6] * inv, xs[7] * inv);
  *(u32x4*)(wout + (((size_t)(h * JT_N + (lane >> 2)) * N_DIM + i) << 5)
            + (lane & 3) * 8) = pk;
}

// ---------------- k2a: LN(m) -> mn bf16 [r=(s,n)][64] ----------------
__global__ __launch_bounds__(256) void k2a_ln_m(
    const float* __restrict__ m, const float* __restrict__ mnw,
    const float* __restrict__ mnb, u16* __restrict__ mn) {
  __shared__ float sw[DM], sb[DM];
  const int tid = threadIdx.x;
  if (tid < DM) { sw[tid] = mnw[tid]; sb[tid] = mnb[tid]; }
  __syncthreads();
  const size_t r = (size_t)blockIdx.x * 256 + tid;
  const float4* mp = (const float4*)(m + r * DM);
  float4 arr[16];
  float sum = 0.f, sq = 0.f;
  #pragma unroll
  for (int q = 0; q < 16; ++q) {
    float4 v = mp[q]; arr[q] = v;
    sum += v.x + v.y + v.z + v.w;
    sq  += v.x * v.x + v.y * v.y + v.z * v.z + v.w * v.w;
  }
  const float mu = sum * (1.f / DM);
  const float rs = rsqrtf(sq * (1.f / DM) - mu * mu + 1e-5f);
  uint4* op = (uint4*)(mn + r * DM);
  #pragma unroll
  for (int q = 0; q < 8; ++q) {
    const float4 a = arr[2 * q], b = arr[2 * q + 1];
    const int c0 = q * 8;
    const float y0 = (a.x - mu) * rs * sw[c0 + 0] + sb[c0 + 0];
    const float y1 = (a.y - mu) * rs * sw[c0 + 1] + sb[c0 + 1];
    const float y2 = (a.z - mu) * rs * sw[c0 + 2] + sb[c0 + 2];
    const float y3 = (a.w - mu) * rs * sw[c0 + 3] + sb[c0 + 3];
    const float y4 = (b.x - mu) * rs * sw[c0 + 4] + sb[c0 + 4];
    const float y5 = (b.y - mu) * rs * sw[c0 + 5] + sb[c0 + 5];
    const float y6 = (b.z - mu) * rs * sw[c0 + 6] + sb[c0 + 6];
    const float y7 = (b.w - mu) * rs * sw[c0 + 7] + sb[c0 + 7];
    uint4 u;
    u.x = pack2(y0, y1); u.y = pack2(y2, y3);
    u.z = pack2(y4, y5); u.w = pack2(y6, y7);
    op[q] = u;
  }
}

// ---------------- k2b: v = mn @ Wm -> vf[h][jt][np][32] ----------------
__global__ __launch_bounds__(256) void k2b_proj(
    const u16* __restrict__ mn, const u16* __restrict__ wmg,
    u16* __restrict__ vf) {
  const int tid = threadIdx.x, lane = tid & 63, wv = tid >> 6;
  const int rbase = (blockIdx.x * 4 + wv) * 16;
  const u16* ap = mn + (size_t)(rbase + (lane & 15)) * DM + ((lane >> 4) & 3) * 8;
  const bf16x8 a0 = ld8(ap);
  const bf16x8 a1 = ld8(ap + 32);
  const u16* bp = wmg + lane * 8;
  const int r0 = rbase + ((lane >> 4) & 3) * 4;
  const int s0 = r0 >> 9;
  const int j0 = r0 & 511;

  f32x4 acc[16];
  #pragma unroll
  for (int cb = 0; cb < 16; ++cb) acc[cb] = (f32x4){0.f, 0.f, 0.f, 0.f};
  #pragma unroll
  for (int cb = 0; cb < 16; ++cb) {
    acc[cb] = mfma16(a0, ld8(bp + cb * 1024), acc[cb]);
    acc[cb] = mfma16(a1, ld8(bp + cb * 1024 + 512), acc[cb]);
  }
  #pragma unroll
  for (int cb = 0; cb < 16; ++cb) {
    const int c = cb * 16 + (lane & 15);
    const int h = c >> 5, k = c & 31;
    const int np = s0 * HD + k;
    const size_t idx = (((size_t)(h * JT_N + (j0 >> 5)) * NP + np) << 5) + (j0 & 31);
    ushort4 pk;
    pk.x = f2bf(acc[cb][0]); pk.y = f2bf(acc[cb][1]);
    pk.z = f2bf(acc[cb][2]); pk.w = f2bf(acc[cb][3]);
    *(ushort4*)(vf + idx) = pk;
  }
}

// ---------------- k3: per-head o = w @ v, counted-vmcnt ring pipeline ----------
// grid dim3(8 h, 4 i-tiles, 64 n'-tiles): XCD k owns head k (idx%8==x).
// Block tile 128x128, BK=32, 4 waves each 64x64 (4x4 16x16 frags).
// 3 LDS slots (prefetch distance 2); s_waitcnt vmcnt(4) per iter — never 0
// in the loop. SWAPPED-operand MFMA: np on reg axis, i on lane axis ->
// epilogue is pure ushort4 stores of o (bf16) into ob[h][i][np].
__global__ __launch_bounds__(256) void k3_pwa(
    const u16* __restrict__ wf, const u16* __restrict__ vf, u16* __restrict__ ob) {
  __shared__ __attribute__((aligned(16))) u16 ring[3][2][128 * BKP];
  const int tid = threadIdx.x, lane = tid & 63, wv = tid >> 6;
  const int wr = wv >> 1, wc = wv & 1;
  const int h = blockIdx.x;
  const int i0 = blockIdx.y * 128;
  const int n0 = blockIdx.z * 128;

  // global K-panel bases (each panel = 128 rows x 32 u16 = 8KB contiguous)
  const char* gA = (const char*)(wf + (((size_t)h * JT_N * N_DIM) + i0) * BKP);
  const char* gB = (const char*)(vf + (((size_t)h * JT_N * NP) + n0) * BKP);

  // per-wave stage: wave wv covers panel bytes [wv*2048, wv*2048+2048)
  const int sbase0 = wv * 2048;
  const int sbase1 = wv * 2048 + 1024;
  const int soff0 = swz(sbase0 + lane * 16);
  const int soff1 = swz(sbase1 + lane * 16);

  f32x4 acc[4][4];
  #pragma unroll
  for (int a = 0; a < 4; ++a)
    #pragma unroll
    for (int b = 0; b < 4; ++b) acc[a][b] = (f32x4){0.f, 0.f, 0.f, 0.f};

  // swizzled LDS read offsets (bytes within panel)
  int offA[4], offB[4];
  #pragma unroll
  for (int f = 0; f < 4; ++f) {
    const int ra = wr * 64 + f * 16 + (lane & 15);
    const int rb = wc * 64 + f * 16 + (lane & 15);
    offA[f] = swz(ra * 64 + ((lane >> 4) & 3) * 16);
    offB[f] = swz(rb * 64 + ((lane >> 4) & 3) * 16);
  }

#define STAGE(jt, slot)                                                  \
  do {                                                                   \
    const char* pA_ = gA + (size_t)(jt) * (N_DIM * BKP * 2);             \
    const char* pB_ = gB + (size_t)(jt) * (NP * BKP * 2);                \
    char* dA_ = (char*)&ring[(slot)][0][0];                              \
    char* dB_ = (char*)&ring[(slot)][1][0];                              \
    gload_lds16(pA_ + soff0, dA_ + sbase0);                              \
    gload_lds16(pA_ + soff1, dA_ + sbase1);                              \
    gload_lds16(pB_ + soff0, dB_ + sbase0);                              \
    gload_lds16(pB_ + soff1, dB_ + sbase1);                              \
  } while (0)

#define COMPUTE(slot)                                                    \
  do {                                                                   \
    const char* cA_ = (const char*)&ring[(slot)][0][0];                  \
    const char* cB_ = (const char*)&ring[(slot)][1][0];                  \
    bf16x8 af_[4], bf_[4];                                               \
    _Pragma("unroll")                                                    \
    for (int f = 0; f < 4; ++f) af_[f] = ld8((const u16*)(cA_ + offA[f]));\
    _Pragma("unroll")                                                    \
    for (int f = 0; f < 4; ++f) bf_[f] = ld8((const u16*)(cB_ + offB[f]));\
    _Pragma("unroll")                                                    \
    for (int fi = 0; fi < 4; ++fi)                                       \
      _Pragma("unroll")                                                  \
      for (int fn = 0; fn < 4; ++fn)                                     \
        acc[fi][fn] = mfma16(bf_[fn], af_[fi], acc[fi][fn]);             \
  } while (0)

  // prologue: tiles 0,1 in flight
  STAGE(0, 0);
  STAGE(1, 1);
  #pragma unroll
  for (int t = 0; t < JT_N - 2; ++t) {
    asm volatile("s_waitcnt vmcnt(4)" ::: "memory");  // tile t landed; t+1 in flight
    BARRIER();
    STAGE(t + 2, (t + 2) % 3);
    COMPUTE(t % 3);
  }
  asm volatile("s_waitcnt vmcnt(4)" ::: "memory");
  BARRIER();
  COMPUTE((JT_N - 2) % 3);
  asm volatile("s_waitcnt vmcnt(0)" ::: "memory");
  BARRIER();
  COMPUTE((JT_N - 1) % 3);
#undef STAGE
#undef COMPUTE

  // epilogue: swapped layout -> lane holds 4 consecutive np for fixed i.
  // pure store of o (bf16) — no RMW.
  #pragma unroll
  for (int fi = 0; fi < 4; ++fi) {
    const int i = i0 + wr * 64 + fi * 16 + (lane & 15);
    #pragma unroll
    for (int fn = 0; fn < 4; ++fn) {
      const int np0 = n0 + wc * 64 + fn * 16 + ((lane >> 4) & 3) * 4;
      ushort4 pk;
      pk.x = f2bf(acc[fi][fn][0]);
      pk.y = f2bf(acc[fi][fn][1]);
      pk.z = f2bf(acc[fi][fn][2]);
      pk.w = f2bf(acc[fi][fn][3]);
      *(ushort4*)(ob + ((size_t)h * N_DIM + i) * NP + np0) = pk;
    }
  }
}

// ---------------- k4: g = sigmoid(mn@Wg) via MFMA; out = (o*g) @ Wo ----------
// Per wave: 16 rows rl=rbase+(lane&15). g computed with swapped-operand MFMA
// (C-layout: lane holds r=lane&15, c=cb*16+q*4+rg), sigmoid'd, bounced through
// padded LDS [r][264] to A-frag layout (lane: r=lane&15, c=ks*32+q*8+t).
__global__ __launch_bounds__(256) void k4_out(
    const u16* __restrict__ ob, const u16* __restrict__ mn,
    const u16* __restrict__ wmg, const u16* __restrict__ wof,
    float* __restrict__ out) {
  __shared__ u16 sg[4][16][264];  // per-wave 16 rows x 256 c, pad 264 (528B)
  const int tid = threadIdx.x, lane = tid & 63, wv = tid >> 6;
  const int q = (lane >> 4) & 3;
  const int rbase = (blockIdx.x * 4 + wv) * 16;
  const int rl = rbase + (lane & 15);
  const int s = rl >> 9, i = rl & 511;

  // ---- g rows via swapped MFMA: D[c, r] = sum_k Wg[k][c] * mn[r][k] ----
  const u16* mp = mn + (size_t)rl * DM + q * 8;
  const bf16x8 b0 = ld8(mp);
  const bf16x8 b1 = ld8(mp + 32);
  const u16* gp = wmg + lane * 8;
  #pragma unroll
  for (int cb = 0; cb < 16; ++cb) {
    f32x4 a = (f32x4){0.f, 0.f, 0.f, 0.f};
    a = mfma16(ld8(gp + (cb + 16) * 1024), b0, a);
    a = mfma16(ld8(gp + (cb + 16) * 1024 + 512), b1, a);
    ushort4 pk;
    pk.x = f2bf(1.f / (1.f + __expf(-a[0])));
    pk.y = f2bf(1.f / (1.f + __expf(-a[1])));
    pk.z = f2bf(1.f / (1.f + __expf(-a[2])));
    pk.w = f2bf(1.f / (1.f + __expf(-a[3])));
    *(ushort4*)&sg[wv][lane & 15][cb * 16 + q * 4] = pk;
  }
  __syncthreads();

  // ---- gated projection: out = (o*g) @ Wo ----
  const u16* ap = ob + (size_t)i * NP + s * HD + q * 8;
  const u16* bp = wof + lane * 8;
  f32x4 acc[4];
  #pragma unroll
  for (int fn = 0; fn < 4; ++fn) acc[fn] = (f32x4){0.f, 0.f, 0.f, 0.f};
  #pragma unroll
  for (int ks = 0; ks < 8; ++ks) {  // ks == head
    const bf16x8 av = ld8(ap + (size_t)ks * 4194304);
    const bf16x8 gv = ld8(&sg[wv][lane & 15][ks * 32 + q * 8]);
    bf16x8 og;
    #pragma unroll
    for (int t = 0; t < 8; ++t)
      ((u16*)&og)[t] = f2bf(bf2f(((const u16*)&av)[t]) * bf2f(((const u16*)&gv)[t]));
    #pragma unroll
    for (int fn = 0; fn < 4; ++fn)
      acc[fn] = mfma16(og, ld8(bp + (fn * 8 + ks) * 512), acc[fn]);
  }
  const int r0 = rbase + q * 4;
  #pragma unroll
  for (int fn = 0; fn < 4; ++fn)
    #pragma unroll
    for (int rg = 0; rg < 4; ++rg)
      out[(size_t)(r0 + rg) * DM + fn * 16 + (lane & 15)] = acc[fn][rg];
}

extern "C" void kernel_launch(void* const* d_in, const int* in_sizes, int n_in,
                              void* d_out, int out_size, void* d_ws, size_t ws_size,
                              hipStream_t stream) {
  const float* m   = (const float*)d_in[0];
  const float* z   = (const float*)d_in[1];
  const float* mnw = (const float*)d_in[2];
  const float* mnb = (const float*)d_in[3];
  const float* znw = (const float*)d_in[4];
  const float* znb = (const float*)d_in[5];
  const float* Wm  = (const float*)d_in[6];
  const float* Wg  = (const float*)d_in[7];
  const float* Wz  = (const float*)d_in[8];
  const float* Wo  = (const float*)d_in[9];
  float* out = (float*)d_out;
  char* ws = (char*)d_ws;

  // ws layout (bytes): wf 4MiB | vf 64MiB | ob 64MiB | mn 16MiB | wmg 64KiB |
  //                    wof 32KiB | wzf 8KiB | t1c 64B
  // bws (8MiB f32) overlaps mn: k1a writes / k1b reads it BEFORE k2a writes mn.
  u16*   wbuf = (u16*)(ws);
  u16*   vf   = (u16*)(ws + ((size_t)4   << 20));
  u16*   ob   = (u16*)(ws + ((size_t)68  << 20));
  u16*   mn   = (u16*)(ws + ((size_t)132 << 20));
  float* bws  = (float*)(ws + ((size_t)132 << 20));
  u16*   wmg  = (u16*)(ws + ((size_t)148 << 20));
  u16*   wof  = (u16*)(ws + ((size_t)148 << 20) + 65536);
  u16*   wzf  = (u16*)(ws + ((size_t)148 << 20) + 98304);
  float* t1c  = (float*)(ws + ((size_t)148 << 20) + 106496);

  k0_prep<<<209, 256, 0, stream>>>(Wm, Wg, Wo, znw, znb, Wz, wmg, wof, wzf, t1c);
  k1a_bias<<<dim3(8, 512), 256, 0, stream>>>(z, wzf, t1c, bws);
  k1b_softmax<<<1024, 256, 0, stream>>>(bws, wbuf);
  k2a_ln_m<<<512, 256, 0, stream>>>(m, mnw, mnb, mn);
  k2b_proj<<<2048, 256, 0, stream>>>(mn, wmg, vf);
  k3_pwa<<<dim3(8, 4, 64), 256, 0, stream>>>(wbuf, vf, ob);
  k4_out<<<2048, 256, 0, stream>>>(ob, mn, wmg, wof, out);
}